// Round 7
// baseline (27284.732 us; speedup 1.0000x reference)
//
#include <hip/hip_runtime.h>
#include <hip/hip_bf16.h>

// GRU B=64 T=1024 D=U=512, reset_after=true. fp32 in/out, bf16 MFMA internally.
//
// Phase 2 v5: XCD-local teams with dual-ring tagged h exchange.
//   64 blocks; team g = blockIdx&7 (co-XCD under round-robin dispatch),
//   role r = blockIdx>>3. Team owns batches [8g,8g+8); role owns units [64r,+64).
//   h words: u64 {hi32 = 0x47520000|step, lo32 = bf16(u)|bf16(u+1)<<16}, ring depth 4.
//   FAST ring: plain stores (write-back L2) + sc0-only loads  -> XCD-L2 latency.
//   SLOW ring: agent-scope atomic stores/loads (r5-proven MALL path).
//   Consumers validate tags; bounded fast retries then proven slow path. No
//   barriers, no flags, no memsets: tags self-validate; prior-replay stale tags
//   can only match with bit-identical data (deterministic replays).
//
// ws layout (bytes):
//   [135168, +524288)        FAST ring u64[8 teams][4 slots][8 batch][256 up]
//   [659456, +524288)        SLOW ring (same geometry)     (both overlay dead Wt)
//   [135168, +1572864)       Wt  bf16 [1536][512]  (dead after xm_gemm)
//   [1708032, +1572864)      Rt  bf16 [1536][512]
//   [3280896, +201326592)    XM  bf16 [T*64][1536] (x@W + b_i), row = t*64+b

typedef __attribute__((ext_vector_type(8))) short short8;
typedef __attribute__((ext_vector_type(4))) float f32x4;
typedef __attribute__((ext_vector_type(4))) unsigned int u32x4;

#define TAGBASE 0x47520000u

__device__ __forceinline__ unsigned short f2bf(float f) {
  unsigned u = __float_as_uint(f);
  u += 0x7FFFu + ((u >> 16) & 1u);   // RNE
  return (unsigned short)(u >> 16);
}
__device__ __forceinline__ float bf2f(unsigned short s) {
  return __uint_as_float(((unsigned)s) << 16);
}

// ---------------- Phase 0: transpose fp32 [R][C] -> bf16 [C][R] ----------------
__global__ void transpose_cast(const float* __restrict__ src,
                               unsigned short* __restrict__ dst,
                               int R, int C) {
  __shared__ float tile[32][33];
  int c0 = blockIdx.x * 32, r0 = blockIdx.y * 32;
  int tx = threadIdx.x, ty = threadIdx.y;
#pragma unroll
  for (int i = 0; i < 4; i++) {
    tile[ty + i * 8][tx] = src[(size_t)(r0 + ty + i * 8) * C + c0 + tx];
  }
  __syncthreads();
#pragma unroll
  for (int i = 0; i < 4; i++) {
    dst[(size_t)(c0 + ty + i * 8) * R + r0 + tx] = f2bf(tile[tx][ty + i * 8]);
  }
}

// ---------------- Phase 1: XM = x @ W + b_i  (bf16 out) ----------------
__global__ __launch_bounds__(256) void xm_gemm(const float* __restrict__ x,
                                               const unsigned short* __restrict__ Wt,
                                               const float* __restrict__ bias,
                                               unsigned short* __restrict__ XM) {
  __shared__ unsigned short As[128][72];
  __shared__ unsigned short Bs[128][72];
  const int tid = threadIdx.x;
  const int bm = blockIdx.x;   // 512
  const int bn = blockIdx.y;   // 12
  const int wave = tid >> 6, lane = tid & 63;
  const int moff = (wave & 1) * 64, noff = (wave >> 1) * 64;

  f32x4 acc[4][4];
#pragma unroll
  for (int mt = 0; mt < 4; mt++)
#pragma unroll
    for (int nt = 0; nt < 4; nt++) acc[mt][nt] = (f32x4){0.f, 0.f, 0.f, 0.f};

  const int r = tid >> 1;
  const int kb = (tid & 1) * 32;
  const int rg = bm * 128 + r;
  const int bb = rg & 63, tt = rg >> 6;

  for (int k0 = 0; k0 < 512; k0 += 64) {
    const f32x4* xp4 = (const f32x4*)(x + ((size_t)bb * 1024 + tt) * 512 + k0 + kb);
#pragma unroll
    for (int j = 0; j < 4; j++) {
      f32x4 lo = xp4[2 * j];
      f32x4 hi = xp4[2 * j + 1];
      union { unsigned short us[8]; short8 v; } u;
      u.us[0] = f2bf(lo[0]); u.us[1] = f2bf(lo[1]); u.us[2] = f2bf(lo[2]); u.us[3] = f2bf(lo[3]);
      u.us[4] = f2bf(hi[0]); u.us[5] = f2bf(hi[1]); u.us[6] = f2bf(hi[2]); u.us[7] = f2bf(hi[3]);
      *(short8*)&As[r][kb + j * 8] = u.v;
    }
    const short8* wp8 = (const short8*)(Wt + (size_t)(bn * 128 + r) * 512 + k0 + kb);
#pragma unroll
    for (int j = 0; j < 4; j++) *(short8*)&Bs[r][kb + j * 8] = wp8[j];
    __syncthreads();

#pragma unroll
    for (int kk = 0; kk < 2; kk++) {
      short8 a[4], b[4];
#pragma unroll
      for (int mt = 0; mt < 4; mt++)
        a[mt] = *(const short8*)&As[moff + mt * 16 + (lane & 15)][kk * 32 + (lane >> 4) * 8];
#pragma unroll
      for (int nt = 0; nt < 4; nt++)
        b[nt] = *(const short8*)&Bs[noff + nt * 16 + (lane & 15)][kk * 32 + (lane >> 4) * 8];
#pragma unroll
      for (int mt = 0; mt < 4; mt++)
#pragma unroll
        for (int nt = 0; nt < 4; nt++)
          acc[mt][nt] = __builtin_amdgcn_mfma_f32_16x16x32_bf16(a[mt], b[nt], acc[mt][nt], 0, 0, 0);
    }
    __syncthreads();
  }

#pragma unroll
  for (int nt = 0; nt < 4; nt++) {
    const int cg = bn * 128 + noff + nt * 16 + (lane & 15);
    const float bi = bias[cg];
#pragma unroll
    for (int mt = 0; mt < 4; mt++) {
      const int rg2 = bm * 128 + moff + mt * 16 + (lane >> 4) * 4;
#pragma unroll
      for (int i = 0; i < 4; i++)
        XM[(size_t)(rg2 + i) * 1536 + cg] = f2bf(acc[mt][nt][i] + bi);
    }
  }
}

// ---------------- Phase 2: recurrence, XCD-local teams, dual-ring tags ----------------
__global__ __launch_bounds__(256, 1) void gru_rec(const unsigned short* __restrict__ Rt,
                                                  const unsigned short* __restrict__ XM,
                                                  const float* __restrict__ bias,
                                                  unsigned long long* fring,
                                                  unsigned long long* sring,
                                                  float* __restrict__ out) {
  const int tid = threadIdx.x;
  const int lane = tid & 63;
  const int wave = tid >> 6;
  const int g = blockIdx.x & 7;       // team (XCD under round-robin)
  const int r = blockIdx.x >> 3;      // role: units [64r, +64)
  const int col = lane & 15;
  const int krow = lane >> 4;         // 0..3
  const int u0 = r * 64 + wave * 16;  // this wave's 16-unit slice

  // weights: Bf[gate][ks] = Rt[gate*512+u0+col][ks*32+krow*8 ..+8]
  short8 Bf[3][16];
#pragma unroll
  for (int g3 = 0; g3 < 3; g3++)
#pragma unroll
    for (int ks = 0; ks < 16; ks++)
      Bf[g3][ks] = *(const short8*)(Rt + (size_t)(g3 * 512 + u0 + col) * 512 + ks * 32 + krow * 8);

  const float br0 = bias[1536 + 0 * 512 + u0 + col];
  const float br1 = bias[1536 + 1 * 512 + u0 + col];
  const float br2 = bias[1536 + 2 * 512 + u0 + col];

  float hreg[4] = {0.f, 0.f, 0.f, 0.f};

  unsigned short xc[3][4], xn[3][4];
#pragma unroll
  for (int g3 = 0; g3 < 3; g3++)
#pragma unroll
    for (int i = 0; i < 4; i++) {
      int batch = g * 8 + ((krow * 4 + i) & 7);
      xc[g3][i] = XM[(size_t)batch * 1536 + g3 * 512 + u0 + col];
    }

  int failcnt = 0;                    // wave-uniform
  bool fast_en = true;

#pragma unroll 1
  for (int t = 0; t < 1024; ++t) {
    f32x4 acc0 = (f32x4){0.f, 0.f, 0.f, 0.f};
    f32x4 acc1 = acc0, acc2 = acc0;

    if (t > 0) {
      const unsigned tagv = TAGBASE | (unsigned)t;
      const size_t choff = (size_t)(g * 8192 + (t & 3) * 2048 + (col & 7) * 256 + krow * 4);
      const unsigned long long* fp = fring + choff;
      const unsigned long long* sp = sring + choff;
      u32x4 q[32];                    // q[ks*2+h] = 16B at byte ks*128 + h*16
      bool ok = false;

      if (fast_en) {
        for (int att = 0; att < 8 && !ok; ++att) {
          asm volatile(
              "global_load_dwordx4 %0, %8, off sc0\n\t"
              "global_load_dwordx4 %1, %8, off offset:16 sc0\n\t"
              "global_load_dwordx4 %2, %8, off offset:128 sc0\n\t"
              "global_load_dwordx4 %3, %8, off offset:144 sc0\n\t"
              "global_load_dwordx4 %4, %8, off offset:256 sc0\n\t"
              "global_load_dwordx4 %5, %8, off offset:272 sc0\n\t"
              "global_load_dwordx4 %6, %8, off offset:384 sc0\n\t"
              "global_load_dwordx4 %7, %8, off offset:400 sc0"
              : "=&v"(q[0]), "=&v"(q[1]), "=&v"(q[2]), "=&v"(q[3]),
                "=&v"(q[4]), "=&v"(q[5]), "=&v"(q[6]), "=&v"(q[7])
              : "v"(fp) : "memory");
          asm volatile(
              "global_load_dwordx4 %0, %8, off offset:512 sc0\n\t"
              "global_load_dwordx4 %1, %8, off offset:528 sc0\n\t"
              "global_load_dwordx4 %2, %8, off offset:640 sc0\n\t"
              "global_load_dwordx4 %3, %8, off offset:656 sc0\n\t"
              "global_load_dwordx4 %4, %8, off offset:768 sc0\n\t"
              "global_load_dwordx4 %5, %8, off offset:784 sc0\n\t"
              "global_load_dwordx4 %6, %8, off offset:896 sc0\n\t"
              "global_load_dwordx4 %7, %8, off offset:912 sc0"
              : "=&v"(q[8]), "=&v"(q[9]), "=&v"(q[10]), "=&v"(q[11]),
                "=&v"(q[12]), "=&v"(q[13]), "=&v"(q[14]), "=&v"(q[15])
              : "v"(fp) : "memory");
          asm volatile(
              "global_load_dwordx4 %0, %8, off offset:1024 sc0\n\t"
              "global_load_dwordx4 %1, %8, off offset:1040 sc0\n\t"
              "global_load_dwordx4 %2, %8, off offset:1152 sc0\n\t"
              "global_load_dwordx4 %3, %8, off offset:1168 sc0\n\t"
              "global_load_dwordx4 %4, %8, off offset:1280 sc0\n\t"
              "global_load_dwordx4 %5, %8, off offset:1296 sc0\n\t"
              "global_load_dwordx4 %6, %8, off offset:1408 sc0\n\t"
              "global_load_dwordx4 %7, %8, off offset:1424 sc0"
              : "=&v"(q[16]), "=&v"(q[17]), "=&v"(q[18]), "=&v"(q[19]),
                "=&v"(q[20]), "=&v"(q[21]), "=&v"(q[22]), "=&v"(q[23])
              : "v"(fp) : "memory");
          asm volatile(
              "global_load_dwordx4 %0, %8, off offset:1536 sc0\n\t"
              "global_load_dwordx4 %1, %8, off offset:1552 sc0\n\t"
              "global_load_dwordx4 %2, %8, off offset:1664 sc0\n\t"
              "global_load_dwordx4 %3, %8, off offset:1680 sc0\n\t"
              "global_load_dwordx4 %4, %8, off offset:1792 sc0\n\t"
              "global_load_dwordx4 %5, %8, off offset:1808 sc0\n\t"
              "global_load_dwordx4 %6, %8, off offset:1920 sc0\n\t"
              "global_load_dwordx4 %7, %8, off offset:1936 sc0"
              : "=&v"(q[24]), "=&v"(q[25]), "=&v"(q[26]), "=&v"(q[27]),
                "=&v"(q[28]), "=&v"(q[29]), "=&v"(q[30]), "=&v"(q[31])
              : "v"(fp) : "memory");
          asm volatile("s_waitcnt vmcnt(0)" ::: "memory");
          __builtin_amdgcn_sched_barrier(0);
          unsigned bad = 0;
#pragma unroll
          for (int i = 0; i < 32; ++i) bad |= (q[i].y ^ tagv) | (q[i].w ^ tagv);
          ok = __all((int)(bad == 0));
          if (!ok) __builtin_amdgcn_s_sleep(1);
        }
        if (ok) {
          failcnt = 0;
        } else {
          if (++failcnt >= 4) fast_en = false;
        }
      }

      if (!ok) {
        // proven agent-scope (MALL) path: always terminates.
        for (;;) {
#pragma unroll
          for (int ks = 0; ks < 16; ++ks)
#pragma unroll
            for (int h = 0; h < 2; ++h) {
              unsigned long long a = __hip_atomic_load(sp + ks * 16 + h * 2,
                                                       __ATOMIC_RELAXED, __HIP_MEMORY_SCOPE_AGENT);
              unsigned long long b = __hip_atomic_load(sp + ks * 16 + h * 2 + 1,
                                                       __ATOMIC_RELAXED, __HIP_MEMORY_SCOPE_AGENT);
              q[ks * 2 + h] = (u32x4){(unsigned)a, (unsigned)(a >> 32),
                                      (unsigned)b, (unsigned)(b >> 32)};
            }
          unsigned bad = 0;
#pragma unroll
          for (int i = 0; i < 32; ++i) bad |= (q[i].y ^ tagv) | (q[i].w ^ tagv);
          if (__all((int)(bad == 0))) break;
          __builtin_amdgcn_s_sleep(2);
        }
      }

      short8 Af[16];
#pragma unroll
      for (int ks = 0; ks < 16; ++ks) {
        u32x4 d = (u32x4){q[ks * 2].x, q[ks * 2].z, q[ks * 2 + 1].x, q[ks * 2 + 1].z};
        Af[ks] = __builtin_bit_cast(short8, d);
      }
#pragma unroll
      for (int ks = 0; ks < 16; ++ks) {
        acc0 = __builtin_amdgcn_mfma_f32_16x16x32_bf16(Af[ks], Bf[0][ks], acc0, 0, 0, 0);
        acc1 = __builtin_amdgcn_mfma_f32_16x16x32_bf16(Af[ks], Bf[1][ks], acc1, 0, 0, 0);
        acc2 = __builtin_amdgcn_mfma_f32_16x16x32_bf16(Af[ks], Bf[2][ks], acc2, 0, 0, 0);
      }
    }

    // gates (fp32); identical arithmetic since r2. krow>=2 rows are dups (unused).
#pragma unroll
    for (int i = 0; i < 4; i++) {
      float hz = acc0[i] + br0;
      float hr = acc1[i] + br1;
      float hh = acc2[i] + br2;
      float xz = bf2f(xc[0][i]);
      float xr = bf2f(xc[1][i]);
      float xh = bf2f(xc[2][i]);
      float z = 1.f / (1.f + __expf(-(xz + hz)));
      float rr = 1.f / (1.f + __expf(-(xr + hr)));
      float y = xh + rr * hh;
      float ay = fabsf(y);
      float e = __expf(-2.f * ay);
      float ca = (1.f - e) / (1.f + e);
      ca = (y < 0.f) ? -ca : ca;
      hreg[i] = z * hreg[i] + (1.f - z) * ca;
    }

    if (t < 1023) {
      const unsigned long long tagbits =
          ((unsigned long long)(TAGBASE | (unsigned)(t + 1))) << 32;
      const size_t sb = (size_t)(g * 8192 + ((t + 1) & 3) * 2048);
#pragma unroll
      for (int i = 0; i < 4; i++) {
        float other = __shfl_xor(hreg[i], 1);
        if (krow < 2 && (col & 1) == 0) {
          unsigned d = (unsigned)f2bf(hreg[i]) | ((unsigned)f2bf(other) << 16);
          unsigned long long val = tagbits | d;
          size_t widx = sb + (size_t)(krow * 4 + i) * 256 + ((u0 + col) >> 1);
          unsigned long long* fq = fring + widx;
          asm volatile("global_store_dwordx2 %0, %1, off" :: "v"(fq), "v"(val) : "memory");
          __hip_atomic_store(sring + widx, val, __ATOMIC_RELAXED, __HIP_MEMORY_SCOPE_AGENT);
        }
      }
    }

    // XM prefetch for next step
    const int tn = (t < 1023) ? t + 1 : 1023;
#pragma unroll
    for (int g3 = 0; g3 < 3; g3++)
#pragma unroll
      for (int i = 0; i < 4; i++) {
        int batch = g * 8 + ((krow * 4 + i) & 7);
        xn[g3][i] = XM[(size_t)(tn * 64 + batch) * 1536 + g3 * 512 + u0 + col];
      }
#pragma unroll
    for (int g3 = 0; g3 < 3; g3++)
#pragma unroll
      for (int i = 0; i < 4; i++) xc[g3][i] = xn[g3][i];
  }

  if (krow < 2) {
#pragma unroll
    for (int i = 0; i < 4; i++)
      out[(size_t)(g * 8 + krow * 4 + i) * 512 + u0 + col] = hreg[i];
  }
}

// ---------------- launch ----------------
extern "C" void kernel_launch(void* const* d_in, const int* in_sizes, int n_in,
                              void* d_out, int out_size, void* d_ws, size_t ws_size,
                              hipStream_t stream) {
  const float* x = (const float*)d_in[0];       // [64][1024][512]
  const float* W = (const float*)d_in[1];       // [512][1536]
  const float* R = (const float*)d_in[2];       // [512][1536]
  const float* bias = (const float*)d_in[3];    // [2][1536]
  float* out = (float*)d_out;

  char* ws = (char*)d_ws;
  unsigned short* Wt = (unsigned short*)(ws + 135168);
  unsigned long long* fring = (unsigned long long*)(ws + 135168);  // overlays Wt
  unsigned long long* sring = (unsigned long long*)(ws + 659456);  // overlays Wt
  unsigned short* Rt = (unsigned short*)(ws + 1708032);
  unsigned short* XM = (unsigned short*)(ws + 3280896);

  transpose_cast<<<dim3(48, 16), dim3(32, 8), 0, stream>>>(W, Wt, 512, 1536);
  transpose_cast<<<dim3(48, 16), dim3(32, 8), 0, stream>>>(R, Rt, 512, 1536);
  xm_gemm<<<dim3(512, 12), dim3(256), 0, stream>>>(x, Wt, bias, XM);
  gru_rec<<<dim3(64), dim3(256), 0, stream>>>(Rt, XM, bias, fring, sring, out);
}

// Round 8
// 16244.406 us; speedup vs baseline: 1.6796x; 1.6796x over previous
//
#include <hip/hip_runtime.h>
#include <hip/hip_bf16.h>

// GRU B=64 T=1024 D=U=512, reset_after=true. fp32 in/out, bf16 MFMA internally.
//
// Phase 2 v6: tag-in-data h exchange through MALL (proven agent atomics),
// speculative full-slice load + tag validation, depth-2 ring, no flags,
// no barriers, no drains. Per-wave-class lockstep bounds drift to <=1 step.
//
// ws layout (bytes):
//   [135168, +262144)        h ring u64[2][64][256] {tag32, bf16x2}
//                            (overlays dead Wt; memset after xm_gemm)
//   [135168, +1572864)       Wt  bf16 [1536][512]  (dead after xm_gemm)
//   [1708032, +1572864)      Rt  bf16 [1536][512]
//   [3280896, +201326592)    XM  bf16 [T*64][1536] (x@W + b_i), row = t*64+b

typedef __attribute__((ext_vector_type(8))) short short8;
typedef __attribute__((ext_vector_type(4))) float f32x4;
typedef __attribute__((ext_vector_type(4))) unsigned int u32x4;

__device__ __forceinline__ unsigned short f2bf(float f) {
  unsigned u = __float_as_uint(f);
  u += 0x7FFFu + ((u >> 16) & 1u);   // RNE
  return (unsigned short)(u >> 16);
}
__device__ __forceinline__ float bf2f(unsigned short s) {
  return __uint_as_float(((unsigned)s) << 16);
}

// ---------------- Phase 0: transpose fp32 [R][C] -> bf16 [C][R] ----------------
__global__ void transpose_cast(const float* __restrict__ src,
                               unsigned short* __restrict__ dst,
                               int R, int C) {
  __shared__ float tile[32][33];
  int c0 = blockIdx.x * 32, r0 = blockIdx.y * 32;
  int tx = threadIdx.x, ty = threadIdx.y;
#pragma unroll
  for (int i = 0; i < 4; i++) {
    tile[ty + i * 8][tx] = src[(size_t)(r0 + ty + i * 8) * C + c0 + tx];
  }
  __syncthreads();
#pragma unroll
  for (int i = 0; i < 4; i++) {
    dst[(size_t)(c0 + ty + i * 8) * R + r0 + tx] = f2bf(tile[tx][ty + i * 8]);
  }
}

// ---------------- Phase 1: XM = x @ W + b_i  (bf16 out) ----------------
__global__ __launch_bounds__(256) void xm_gemm(const float* __restrict__ x,
                                               const unsigned short* __restrict__ Wt,
                                               const float* __restrict__ bias,
                                               unsigned short* __restrict__ XM) {
  __shared__ unsigned short As[128][72];
  __shared__ unsigned short Bs[128][72];
  const int tid = threadIdx.x;
  const int bm = blockIdx.x;   // 512
  const int bn = blockIdx.y;   // 12
  const int wave = tid >> 6, lane = tid & 63;
  const int moff = (wave & 1) * 64, noff = (wave >> 1) * 64;

  f32x4 acc[4][4];
#pragma unroll
  for (int mt = 0; mt < 4; mt++)
#pragma unroll
    for (int nt = 0; nt < 4; nt++) acc[mt][nt] = (f32x4){0.f, 0.f, 0.f, 0.f};

  const int r = tid >> 1;
  const int kb = (tid & 1) * 32;
  const int rg = bm * 128 + r;
  const int bb = rg & 63, tt = rg >> 6;

  for (int k0 = 0; k0 < 512; k0 += 64) {
    const f32x4* xp4 = (const f32x4*)(x + ((size_t)bb * 1024 + tt) * 512 + k0 + kb);
#pragma unroll
    for (int j = 0; j < 4; j++) {
      f32x4 lo = xp4[2 * j];
      f32x4 hi = xp4[2 * j + 1];
      union { unsigned short us[8]; short8 v; } u;
      u.us[0] = f2bf(lo[0]); u.us[1] = f2bf(lo[1]); u.us[2] = f2bf(lo[2]); u.us[3] = f2bf(lo[3]);
      u.us[4] = f2bf(hi[0]); u.us[5] = f2bf(hi[1]); u.us[6] = f2bf(hi[2]); u.us[7] = f2bf(hi[3]);
      *(short8*)&As[r][kb + j * 8] = u.v;
    }
    const short8* wp8 = (const short8*)(Wt + (size_t)(bn * 128 + r) * 512 + k0 + kb);
#pragma unroll
    for (int j = 0; j < 4; j++) *(short8*)&Bs[r][kb + j * 8] = wp8[j];
    __syncthreads();

#pragma unroll
    for (int kk = 0; kk < 2; kk++) {
      short8 a[4], b[4];
#pragma unroll
      for (int mt = 0; mt < 4; mt++)
        a[mt] = *(const short8*)&As[moff + mt * 16 + (lane & 15)][kk * 32 + (lane >> 4) * 8];
#pragma unroll
      for (int nt = 0; nt < 4; nt++)
        b[nt] = *(const short8*)&Bs[noff + nt * 16 + (lane & 15)][kk * 32 + (lane >> 4) * 8];
#pragma unroll
      for (int mt = 0; mt < 4; mt++)
#pragma unroll
        for (int nt = 0; nt < 4; nt++)
          acc[mt][nt] = __builtin_amdgcn_mfma_f32_16x16x32_bf16(a[mt], b[nt], acc[mt][nt], 0, 0, 0);
    }
    __syncthreads();
  }

#pragma unroll
  for (int nt = 0; nt < 4; nt++) {
    const int cg = bn * 128 + noff + nt * 16 + (lane & 15);
    const float bi = bias[cg];
#pragma unroll
    for (int mt = 0; mt < 4; mt++) {
      const int rg2 = bm * 128 + moff + mt * 16 + (lane >> 4) * 4;
#pragma unroll
      for (int i = 0; i < 4; i++)
        XM[(size_t)(rg2 + i) * 1536 + cg] = f2bf(acc[mt][nt][i] + bi);
    }
  }
}

// ---------------- Phase 2: recurrence, tagged depth-2 ring through MALL ----------------
// 32 blocks x 256 threads; waves free-run (no intra-block barriers).
// Wave (blk,w) produces units [blk*16,+16) for batches [w*16,+16) and consumes
// ALL units for batches [w*16,+16). Ring word [slot][batch][unitpair]:
// u64 {hi32 = step+1, lo32 = bf16(u)|bf16(u+1)<<16}, slot = step&1.
// Depth-2 safety: a validated load of step t-1 from block b implies b completed
// its validated load of t-2 (stores are data-dependent on loads), so the
// producer of h_t may overwrite h_{t-2}.
__global__ __launch_bounds__(256, 1) void gru_rec(const unsigned short* __restrict__ Rt,
                                                  const unsigned short* __restrict__ XM,
                                                  const float* __restrict__ bias,
                                                  unsigned long long* ring,
                                                  float* __restrict__ out) {
  const int tid = threadIdx.x;
  const int lane = tid & 63;
  const int wave = tid >> 6;          // 0..3 -> batches wave*16..+15
  const int blk = blockIdx.x;         // 0..31 -> units blk*16..+15
  const int u0 = blk * 16;
  const int col = lane & 15;
  const int krow = lane >> 4;         // 0..3

  // B fragments: Rt[g*512+u0+col][k], k = ks*32 + krow*8 + j
  short8 Bf[3][16];
#pragma unroll
  for (int g = 0; g < 3; g++)
#pragma unroll
    for (int ks = 0; ks < 16; ks++)
      Bf[g][ks] = *(const short8*)(Rt + (size_t)(g * 512 + u0 + col) * 512 + ks * 32 + krow * 8);

  const float br0 = bias[1536 + 0 * 512 + u0 + col];
  const float br1 = bias[1536 + 1 * 512 + u0 + col];
  const float br2 = bias[1536 + 2 * 512 + u0 + col];

  float hreg[4] = {0.f, 0.f, 0.f, 0.f};   // own (batch,unit) state, fp32

  unsigned short xc[3][4], xn[3][4];
#pragma unroll
  for (int g = 0; g < 3; g++)
#pragma unroll
    for (int i = 0; i < 4; i++) {
      int batch = wave * 16 + krow * 4 + i;
      xc[g][i] = XM[(size_t)batch * 1536 + g * 512 + u0 + col];
    }

#pragma unroll 1
  for (int t = 0; t < 1024; ++t) {
    f32x4 acc0 = (f32x4){0.f, 0.f, 0.f, 0.f};
    f32x4 acc1 = acc0, acc2 = acc0;
    const int tn = (t < 1023) ? t + 1 : 1023;

    if (t > 0) {
      // consumer: speculative full-slice load + tag validation (retry until valid).
      const unsigned long long* hp =
          ring + (size_t)((t + 1) & 1) * 16384 + (size_t)(wave * 16 + col) * 256 + krow * 4;
      const unsigned tagv = (unsigned)t;
      short8 Af[16];
      for (;;) {
        unsigned bad = 0;
#pragma unroll
        for (int ks = 0; ks < 16; ++ks) {
          unsigned long long a0 = __hip_atomic_load(hp + ks * 16 + 0, __ATOMIC_RELAXED,
                                                    __HIP_MEMORY_SCOPE_AGENT);
          unsigned long long a1 = __hip_atomic_load(hp + ks * 16 + 1, __ATOMIC_RELAXED,
                                                    __HIP_MEMORY_SCOPE_AGENT);
          unsigned long long a2 = __hip_atomic_load(hp + ks * 16 + 2, __ATOMIC_RELAXED,
                                                    __HIP_MEMORY_SCOPE_AGENT);
          unsigned long long a3 = __hip_atomic_load(hp + ks * 16 + 3, __ATOMIC_RELAXED,
                                                    __HIP_MEMORY_SCOPE_AGENT);
          bad |= (((unsigned)(a0 >> 32)) ^ tagv) | (((unsigned)(a1 >> 32)) ^ tagv) |
                 (((unsigned)(a2 >> 32)) ^ tagv) | (((unsigned)(a3 >> 32)) ^ tagv);
          u32x4 d = (u32x4){(unsigned)a0, (unsigned)a1, (unsigned)a2, (unsigned)a3};
          Af[ks] = __builtin_bit_cast(short8, d);
        }
        if (__all((int)(bad == 0))) break;
        __builtin_amdgcn_s_sleep(1);
      }

      // XM prefetch for t+1 (issued between load and MFMA; hides under compute)
#pragma unroll
      for (int g = 0; g < 3; g++)
#pragma unroll
        for (int i = 0; i < 4; i++) {
          int batch = wave * 16 + krow * 4 + i;
          xn[g][i] = XM[(size_t)(tn * 64 + batch) * 1536 + g * 512 + u0 + col];
        }

#pragma unroll
      for (int ks = 0; ks < 16; ++ks) {
        acc0 = __builtin_amdgcn_mfma_f32_16x16x32_bf16(Af[ks], Bf[0][ks], acc0, 0, 0, 0);
        acc1 = __builtin_amdgcn_mfma_f32_16x16x32_bf16(Af[ks], Bf[1][ks], acc1, 0, 0, 0);
        acc2 = __builtin_amdgcn_mfma_f32_16x16x32_bf16(Af[ks], Bf[2][ks], acc2, 0, 0, 0);
      }
    } else {
#pragma unroll
      for (int g = 0; g < 3; g++)
#pragma unroll
        for (int i = 0; i < 4; i++) {
          int batch = wave * 16 + krow * 4 + i;
          xn[g][i] = XM[(size_t)(tn * 64 + batch) * 1536 + g * 512 + u0 + col];
        }
    }

    // gates (fp32); identical arithmetic since r2.
#pragma unroll
    for (int i = 0; i < 4; i++) {
      float hz = acc0[i] + br0;
      float hr = acc1[i] + br1;
      float hh = acc2[i] + br2;
      float xz = bf2f(xc[0][i]);
      float xr = bf2f(xc[1][i]);
      float xh = bf2f(xc[2][i]);
      float z = 1.f / (1.f + __expf(-(xz + hz)));
      float r = 1.f / (1.f + __expf(-(xr + hr)));
      float y = xh + r * hh;
      float ay = fabsf(y);
      float e = __expf(-2.f * ay);
      float ca = (1.f - e) / (1.f + e);          // |tanh|
      ca = (y < 0.f) ? -ca : ca;
      hreg[i] = z * hreg[i] + (1.f - z) * ca;
    }

    if (t < 1023) {
      // producer: tagged u64 stores (relaxed agent). Data-dependent on this
      // step's validated load -> depth-2 overwrite safety.
      const size_t sb = (size_t)(t & 1) * 16384;
      const unsigned long long tagbits = ((unsigned long long)(unsigned)(t + 1)) << 32;
#pragma unroll
      for (int i = 0; i < 4; i++) {
        int batch = wave * 16 + krow * 4 + i;
        float other = __shfl_xor(hreg[i], 1);
        if ((col & 1) == 0) {
          unsigned d = (unsigned)f2bf(hreg[i]) | ((unsigned)f2bf(other) << 16);
          __hip_atomic_store(ring + sb + (size_t)batch * 256 + ((u0 + col) >> 1),
                             tagbits | (unsigned long long)d,
                             __ATOMIC_RELAXED, __HIP_MEMORY_SCOPE_AGENT);
        }
      }
    }

#pragma unroll
    for (int g = 0; g < 3; g++)
#pragma unroll
      for (int i = 0; i < 4; i++) xc[g][i] = xn[g][i];
  }

#pragma unroll
  for (int i = 0; i < 4; i++) {
    int batch = wave * 16 + krow * 4 + i;
    out[(size_t)batch * 512 + u0 + col] = hreg[i];
  }
}

// ---------------- launch ----------------
extern "C" void kernel_launch(void* const* d_in, const int* in_sizes, int n_in,
                              void* d_out, int out_size, void* d_ws, size_t ws_size,
                              hipStream_t stream) {
  const float* x = (const float*)d_in[0];       // [64][1024][512]
  const float* W = (const float*)d_in[1];       // [512][1536]
  const float* R = (const float*)d_in[2];       // [512][1536]
  const float* bias = (const float*)d_in[3];    // [2][1536]
  float* out = (float*)d_out;

  char* ws = (char*)d_ws;
  unsigned short* Wt = (unsigned short*)(ws + 135168);
  unsigned long long* ring = (unsigned long long*)(ws + 135168);  // overlays Wt
  unsigned short* Rt = (unsigned short*)(ws + 1708032);
  unsigned short* XM = (unsigned short*)(ws + 3280896);

  transpose_cast<<<dim3(48, 16), dim3(32, 8), 0, stream>>>(W, Wt, 512, 1536);
  transpose_cast<<<dim3(48, 16), dim3(32, 8), 0, stream>>>(R, Rt, 512, 1536);
  xm_gemm<<<dim3(512, 12), dim3(256), 0, stream>>>(x, Wt, bias, XM);
  // Wt dead now; zero the tagged ring that overlays it (tag 0 matches no step;
  // kernel-boundary ordering makes the zeros visible to gru_rec).
  hipMemsetAsync(ring, 0, 2ull * 64 * 256 * 8, stream);
  gru_rec<<<dim3(32), dim3(256), 0, stream>>>(Rt, XM, bias, ring, out);
}

// Round 9
// 11638.779 us; speedup vs baseline: 2.3443x; 1.3957x over previous
//
#include <hip/hip_runtime.h>
#include <hip/hip_bf16.h>

// GRU B=64 T=1024 D=U=512, reset_after=true. fp32 in/out, bf16 MFMA internally.
//
// Phase 2 v7: hybrid exchange. Producers store TAGGED h words (u64{tag=t+1,
// bf16x2}, relaxed agent atomics, depth-2 ring) and publish per-block flags
// after vmcnt-drain (r5-proven pacing). Consumers first try a BOUNDED
// tag-validated speculative load (skips 1.5 visibility hops when data already
// arrived); on failure fall back to the r5-proven flag-wait + validated load.
// Flags keep all blocks lockstep => no free-run retry storms (r6/r8 lesson).
//
// ws layout (bytes):
//   [0,128)                  flags[32]  (memset at launch start)
//   [135168, +262144)        h ring u64[2][64][256] {tag32, bf16x2}
//                            (overlays dead Wt; memset after xm_gemm)
//   [135168, +1572864)       Wt  bf16 [1536][512]  (dead after xm_gemm)
//   [1708032, +1572864)      Rt  bf16 [1536][512]
//   [3280896, +201326592)    XM  bf16 [T*64][1536] (x@W + b_i), row = t*64+b

typedef __attribute__((ext_vector_type(8))) short short8;
typedef __attribute__((ext_vector_type(4))) float f32x4;
typedef __attribute__((ext_vector_type(4))) unsigned int u32x4;

__device__ __forceinline__ unsigned short f2bf(float f) {
  unsigned u = __float_as_uint(f);
  u += 0x7FFFu + ((u >> 16) & 1u);   // RNE
  return (unsigned short)(u >> 16);
}
__device__ __forceinline__ float bf2f(unsigned short s) {
  return __uint_as_float(((unsigned)s) << 16);
}

// ---------------- Phase 0: transpose fp32 [R][C] -> bf16 [C][R] ----------------
__global__ void transpose_cast(const float* __restrict__ src,
                               unsigned short* __restrict__ dst,
                               int R, int C) {
  __shared__ float tile[32][33];
  int c0 = blockIdx.x * 32, r0 = blockIdx.y * 32;
  int tx = threadIdx.x, ty = threadIdx.y;
#pragma unroll
  for (int i = 0; i < 4; i++) {
    tile[ty + i * 8][tx] = src[(size_t)(r0 + ty + i * 8) * C + c0 + tx];
  }
  __syncthreads();
#pragma unroll
  for (int i = 0; i < 4; i++) {
    dst[(size_t)(c0 + ty + i * 8) * R + r0 + tx] = f2bf(tile[tx][ty + i * 8]);
  }
}

// ---------------- Phase 1: XM = x @ W + b_i  (bf16 out) ----------------
__global__ __launch_bounds__(256) void xm_gemm(const float* __restrict__ x,
                                               const unsigned short* __restrict__ Wt,
                                               const float* __restrict__ bias,
                                               unsigned short* __restrict__ XM) {
  __shared__ unsigned short As[128][72];
  __shared__ unsigned short Bs[128][72];
  const int tid = threadIdx.x;
  const int bm = blockIdx.x;   // 512
  const int bn = blockIdx.y;   // 12
  const int wave = tid >> 6, lane = tid & 63;
  const int moff = (wave & 1) * 64, noff = (wave >> 1) * 64;

  f32x4 acc[4][4];
#pragma unroll
  for (int mt = 0; mt < 4; mt++)
#pragma unroll
    for (int nt = 0; nt < 4; nt++) acc[mt][nt] = (f32x4){0.f, 0.f, 0.f, 0.f};

  const int r = tid >> 1;
  const int kb = (tid & 1) * 32;
  const int rg = bm * 128 + r;
  const int bb = rg & 63, tt = rg >> 6;

  for (int k0 = 0; k0 < 512; k0 += 64) {
    const f32x4* xp4 = (const f32x4*)(x + ((size_t)bb * 1024 + tt) * 512 + k0 + kb);
#pragma unroll
    for (int j = 0; j < 4; j++) {
      f32x4 lo = xp4[2 * j];
      f32x4 hi = xp4[2 * j + 1];
      union { unsigned short us[8]; short8 v; } u;
      u.us[0] = f2bf(lo[0]); u.us[1] = f2bf(lo[1]); u.us[2] = f2bf(lo[2]); u.us[3] = f2bf(lo[3]);
      u.us[4] = f2bf(hi[0]); u.us[5] = f2bf(hi[1]); u.us[6] = f2bf(hi[2]); u.us[7] = f2bf(hi[3]);
      *(short8*)&As[r][kb + j * 8] = u.v;
    }
    const short8* wp8 = (const short8*)(Wt + (size_t)(bn * 128 + r) * 512 + k0 + kb);
#pragma unroll
    for (int j = 0; j < 4; j++) *(short8*)&Bs[r][kb + j * 8] = wp8[j];
    __syncthreads();

#pragma unroll
    for (int kk = 0; kk < 2; kk++) {
      short8 a[4], b[4];
#pragma unroll
      for (int mt = 0; mt < 4; mt++)
        a[mt] = *(const short8*)&As[moff + mt * 16 + (lane & 15)][kk * 32 + (lane >> 4) * 8];
#pragma unroll
      for (int nt = 0; nt < 4; nt++)
        b[nt] = *(const short8*)&Bs[noff + nt * 16 + (lane & 15)][kk * 32 + (lane >> 4) * 8];
#pragma unroll
      for (int mt = 0; mt < 4; mt++)
#pragma unroll
        for (int nt = 0; nt < 4; nt++)
          acc[mt][nt] = __builtin_amdgcn_mfma_f32_16x16x32_bf16(a[mt], b[nt], acc[mt][nt], 0, 0, 0);
    }
    __syncthreads();
  }

#pragma unroll
  for (int nt = 0; nt < 4; nt++) {
    const int cg = bn * 128 + noff + nt * 16 + (lane & 15);
    const float bi = bias[cg];
#pragma unroll
    for (int mt = 0; mt < 4; mt++) {
      const int rg2 = bm * 128 + moff + mt * 16 + (lane >> 4) * 4;
#pragma unroll
      for (int i = 0; i < 4; i++)
        XM[(size_t)(rg2 + i) * 1536 + cg] = f2bf(acc[mt][nt][i] + bi);
    }
  }
}

// ---------------- Phase 2: recurrence, hybrid tagged ring + flag pacing ----------------
__global__ __launch_bounds__(256, 1) void gru_rec(const unsigned short* __restrict__ Rt,
                                                  const unsigned short* __restrict__ XM,
                                                  const float* __restrict__ bias,
                                                  unsigned long long* ring,
                                                  unsigned int* flags,
                                                  float* __restrict__ out) {
  const int tid = threadIdx.x;
  const int lane = tid & 63;
  const int wave = tid >> 6;          // 0..3 -> batches wave*16..+15
  const int blk = blockIdx.x;         // 0..31 -> units blk*16..+15
  const int u0 = blk * 16;
  const int col = lane & 15;
  const int krow = lane >> 4;         // 0..3

  // B fragments: Rt[g*512+u0+col][k], k = ks*32 + krow*8 + j
  short8 Bf[3][16];
#pragma unroll
  for (int g = 0; g < 3; g++)
#pragma unroll
    for (int ks = 0; ks < 16; ks++)
      Bf[g][ks] = *(const short8*)(Rt + (size_t)(g * 512 + u0 + col) * 512 + ks * 32 + krow * 8);

  const float br0 = bias[1536 + 0 * 512 + u0 + col];
  const float br1 = bias[1536 + 1 * 512 + u0 + col];
  const float br2 = bias[1536 + 2 * 512 + u0 + col];

  float hreg[4] = {0.f, 0.f, 0.f, 0.f};

  unsigned short xc[3][4], xn[3][4];
#pragma unroll
  for (int g = 0; g < 3; g++)
#pragma unroll
    for (int i = 0; i < 4; i++) {
      int batch = wave * 16 + krow * 4 + i;
      xc[g][i] = XM[(size_t)batch * 1536 + g * 512 + u0 + col];
    }

#pragma unroll 1
  for (int t = 0; t < 1024; ++t) {
    f32x4 acc0 = (f32x4){0.f, 0.f, 0.f, 0.f};
    f32x4 acc1 = acc0, acc2 = acc0;
    const int tn = (t < 1023) ? t + 1 : 1023;

    if (t > 0) {
      const unsigned tagv = (unsigned)t;
      const unsigned long long* hp =
          ring + (size_t)((t + 1) & 1) * 16384 + (size_t)(wave * 16 + col) * 256 + krow * 4;
      short8 Af[16];

      // one tag-validated slice load attempt
      auto try_load = [&]() -> unsigned {
        unsigned bad = 0;
#pragma unroll
        for (int ks = 0; ks < 16; ++ks) {
          unsigned long long a0 = __hip_atomic_load(hp + ks * 16 + 0, __ATOMIC_RELAXED,
                                                    __HIP_MEMORY_SCOPE_AGENT);
          unsigned long long a1 = __hip_atomic_load(hp + ks * 16 + 1, __ATOMIC_RELAXED,
                                                    __HIP_MEMORY_SCOPE_AGENT);
          unsigned long long a2 = __hip_atomic_load(hp + ks * 16 + 2, __ATOMIC_RELAXED,
                                                    __HIP_MEMORY_SCOPE_AGENT);
          unsigned long long a3 = __hip_atomic_load(hp + ks * 16 + 3, __ATOMIC_RELAXED,
                                                    __HIP_MEMORY_SCOPE_AGENT);
          bad |= (((unsigned)(a0 >> 32)) ^ tagv) | (((unsigned)(a1 >> 32)) ^ tagv) |
                 (((unsigned)(a2 >> 32)) ^ tagv) | (((unsigned)(a3 >> 32)) ^ tagv);
          u32x4 d = (u32x4){(unsigned)a0, (unsigned)a1, (unsigned)a2, (unsigned)a3};
          Af[ks] = __builtin_bit_cast(short8, d);
        }
        return bad;
      };

      // FAST: bounded speculative attempts (skips flag hops when data arrived)
      bool ok = false;
      for (int att = 0; att < 6 && !ok; ++att) {
        if (att) __builtin_amdgcn_s_sleep(1);
        ok = __all((int)(try_load() == 0));
      }
      // FALLBACK: r5-proven flag-wait, then validated load (terminates).
      if (!ok) {
        for (;;) {
          for (;;) {
            unsigned v = (lane < 32)
                ? __hip_atomic_load(&flags[lane], __ATOMIC_RELAXED, __HIP_MEMORY_SCOPE_AGENT)
                : tagv;
            if (__all((int)(v >= tagv))) break;
            __builtin_amdgcn_s_sleep(2);
          }
          if (__all((int)(try_load() == 0))) break;
          __builtin_amdgcn_s_sleep(1);
        }
      }

      // XM prefetch for t+1 (hides under MFMA)
#pragma unroll
      for (int g = 0; g < 3; g++)
#pragma unroll
        for (int i = 0; i < 4; i++) {
          int batch = wave * 16 + krow * 4 + i;
          xn[g][i] = XM[(size_t)(tn * 64 + batch) * 1536 + g * 512 + u0 + col];
        }

#pragma unroll
      for (int ks = 0; ks < 16; ++ks) {
        acc0 = __builtin_amdgcn_mfma_f32_16x16x32_bf16(Af[ks], Bf[0][ks], acc0, 0, 0, 0);
        acc1 = __builtin_amdgcn_mfma_f32_16x16x32_bf16(Af[ks], Bf[1][ks], acc1, 0, 0, 0);
        acc2 = __builtin_amdgcn_mfma_f32_16x16x32_bf16(Af[ks], Bf[2][ks], acc2, 0, 0, 0);
      }
    } else {
#pragma unroll
      for (int g = 0; g < 3; g++)
#pragma unroll
        for (int i = 0; i < 4; i++) {
          int batch = wave * 16 + krow * 4 + i;
          xn[g][i] = XM[(size_t)(tn * 64 + batch) * 1536 + g * 512 + u0 + col];
        }
    }

    // gates (fp32); identical arithmetic since r2.
#pragma unroll
    for (int i = 0; i < 4; i++) {
      float hz = acc0[i] + br0;
      float hr = acc1[i] + br1;
      float hh = acc2[i] + br2;
      float xz = bf2f(xc[0][i]);
      float xr = bf2f(xc[1][i]);
      float xh = bf2f(xc[2][i]);
      float z = 1.f / (1.f + __expf(-(xz + hz)));
      float r = 1.f / (1.f + __expf(-(xr + hr)));
      float y = xh + r * hh;
      float ay = fabsf(y);
      float e = __expf(-2.f * ay);
      float ca = (1.f - e) / (1.f + e);          // |tanh|
      ca = (y < 0.f) ? -ca : ca;
      hreg[i] = z * hreg[i] + (1.f - z) * ca;
    }

    if (t < 1023) {
      // producer: tagged u64 stores (relaxed agent), then drain + barrier +
      // flag publish (r5-proven ordering: flag>=t+1 implies h_t visible).
      const size_t sb = (size_t)(t & 1) * 16384;
      const unsigned long long tagbits = ((unsigned long long)(unsigned)(t + 1)) << 32;
#pragma unroll
      for (int i = 0; i < 4; i++) {
        int batch = wave * 16 + krow * 4 + i;
        float other = __shfl_xor(hreg[i], 1);
        if ((col & 1) == 0) {
          unsigned d = (unsigned)f2bf(hreg[i]) | ((unsigned)f2bf(other) << 16);
          __hip_atomic_store(ring + sb + (size_t)batch * 256 + ((u0 + col) >> 1),
                             tagbits | (unsigned long long)d,
                             __ATOMIC_RELAXED, __HIP_MEMORY_SCOPE_AGENT);
        }
      }
      asm volatile("s_waitcnt vmcnt(0)" ::: "memory");
      __syncthreads();
      if (tid == 0) {
        __hip_atomic_store(&flags[blk], (unsigned)(t + 1),
                           __ATOMIC_RELAXED, __HIP_MEMORY_SCOPE_AGENT);
      }
    }

#pragma unroll
    for (int g = 0; g < 3; g++)
#pragma unroll
      for (int i = 0; i < 4; i++) xc[g][i] = xn[g][i];
  }

#pragma unroll
  for (int i = 0; i < 4; i++) {
    int batch = wave * 16 + krow * 4 + i;
    out[(size_t)batch * 512 + u0 + col] = hreg[i];
  }
}

// ---------------- launch ----------------
extern "C" void kernel_launch(void* const* d_in, const int* in_sizes, int n_in,
                              void* d_out, int out_size, void* d_ws, size_t ws_size,
                              hipStream_t stream) {
  const float* x = (const float*)d_in[0];       // [64][1024][512]
  const float* W = (const float*)d_in[1];       // [512][1536]
  const float* R = (const float*)d_in[2];       // [512][1536]
  const float* bias = (const float*)d_in[3];    // [2][1536]
  float* out = (float*)d_out;

  char* ws = (char*)d_ws;
  unsigned int* flags = (unsigned int*)(ws + 0);
  unsigned short* Wt = (unsigned short*)(ws + 135168);
  unsigned long long* ring = (unsigned long long*)(ws + 135168);  // overlays Wt
  unsigned short* Rt = (unsigned short*)(ws + 1708032);
  unsigned short* XM = (unsigned short*)(ws + 3280896);

  hipMemsetAsync(flags, 0, 4096, stream);
  transpose_cast<<<dim3(48, 16), dim3(32, 8), 0, stream>>>(W, Wt, 512, 1536);
  transpose_cast<<<dim3(48, 16), dim3(32, 8), 0, stream>>>(R, Rt, 512, 1536);
  xm_gemm<<<dim3(512, 12), dim3(256), 0, stream>>>(x, Wt, bias, XM);
  // Wt dead now; zero the tagged ring (tag 0 matches no step).
  hipMemsetAsync(ring, 0, 2ull * 64 * 256 * 8, stream);
  gru_rec<<<dim3(32), dim3(256), 0, stream>>>(Rt, XM, bias, ring, flags, out);
}

// Round 10
// 9924.453 us; speedup vs baseline: 2.7492x; 1.1727x over previous
//
#include <hip/hip_runtime.h>
#include <hip/hip_bf16.h>

// GRU B=64 T=1024 D=U=512, reset_after=true. fp32 in/out, bf16 MFMA internally.
//
// Phase 2 v8: minimal-hop tagged exchange. Producers store tagged u64 h words
// (depth-2 ring, relaxed agent atomics) with NO drain / barrier / flags.
// Consumers poll a 1-word-per-producer sentinel set (flag-poll cost), then do
// ONE bulk slice load validated by per-word tags, with cheap bounded retries.
// Dataflow bounds inter-block drift to <=1 step (produce t+1 requires having
// validated everyone's t) -- no pacing flags needed; hang-free by induction.
//
// ws layout (bytes):
//   [135168, +262144)        h ring u64[2][64][256] {tag32, bf16x2}
//                            (overlays dead Wt; memset after xm_gemm)
//   [135168, +1572864)       Wt  bf16 [1536][512]  (dead after xm_gemm)
//   [1708032, +1572864)      Rt  bf16 [1536][512]
//   [3280896, +201326592)    XM  bf16 [T*64][1536] (x@W + b_i), row = t*64+b

typedef __attribute__((ext_vector_type(8))) short short8;
typedef __attribute__((ext_vector_type(4))) float f32x4;
typedef __attribute__((ext_vector_type(4))) unsigned int u32x4;

__device__ __forceinline__ unsigned short f2bf(float f) {
  unsigned u = __float_as_uint(f);
  u += 0x7FFFu + ((u >> 16) & 1u);   // RNE
  return (unsigned short)(u >> 16);
}
__device__ __forceinline__ float bf2f(unsigned short s) {
  return __uint_as_float(((unsigned)s) << 16);
}

// ---------------- Phase 0: transpose fp32 [R][C] -> bf16 [C][R] ----------------
__global__ void transpose_cast(const float* __restrict__ src,
                               unsigned short* __restrict__ dst,
                               int R, int C) {
  __shared__ float tile[32][33];
  int c0 = blockIdx.x * 32, r0 = blockIdx.y * 32;
  int tx = threadIdx.x, ty = threadIdx.y;
#pragma unroll
  for (int i = 0; i < 4; i++) {
    tile[ty + i * 8][tx] = src[(size_t)(r0 + ty + i * 8) * C + c0 + tx];
  }
  __syncthreads();
#pragma unroll
  for (int i = 0; i < 4; i++) {
    dst[(size_t)(c0 + ty + i * 8) * R + r0 + tx] = f2bf(tile[tx][ty + i * 8]);
  }
}

// ---------------- Phase 1: XM = x @ W + b_i  (bf16 out) ----------------
__global__ __launch_bounds__(256) void xm_gemm(const float* __restrict__ x,
                                               const unsigned short* __restrict__ Wt,
                                               const float* __restrict__ bias,
                                               unsigned short* __restrict__ XM) {
  __shared__ unsigned short As[128][72];
  __shared__ unsigned short Bs[128][72];
  const int tid = threadIdx.x;
  const int bm = blockIdx.x;   // 512
  const int bn = blockIdx.y;   // 12
  const int wave = tid >> 6, lane = tid & 63;
  const int moff = (wave & 1) * 64, noff = (wave >> 1) * 64;

  f32x4 acc[4][4];
#pragma unroll
  for (int mt = 0; mt < 4; mt++)
#pragma unroll
    for (int nt = 0; nt < 4; nt++) acc[mt][nt] = (f32x4){0.f, 0.f, 0.f, 0.f};

  const int r = tid >> 1;
  const int kb = (tid & 1) * 32;
  const int rg = bm * 128 + r;
  const int bb = rg & 63, tt = rg >> 6;

  for (int k0 = 0; k0 < 512; k0 += 64) {
    const f32x4* xp4 = (const f32x4*)(x + ((size_t)bb * 1024 + tt) * 512 + k0 + kb);
#pragma unroll
    for (int j = 0; j < 4; j++) {
      f32x4 lo = xp4[2 * j];
      f32x4 hi = xp4[2 * j + 1];
      union { unsigned short us[8]; short8 v; } u;
      u.us[0] = f2bf(lo[0]); u.us[1] = f2bf(lo[1]); u.us[2] = f2bf(lo[2]); u.us[3] = f2bf(lo[3]);
      u.us[4] = f2bf(hi[0]); u.us[5] = f2bf(hi[1]); u.us[6] = f2bf(hi[2]); u.us[7] = f2bf(hi[3]);
      *(short8*)&As[r][kb + j * 8] = u.v;
    }
    const short8* wp8 = (const short8*)(Wt + (size_t)(bn * 128 + r) * 512 + k0 + kb);
#pragma unroll
    for (int j = 0; j < 4; j++) *(short8*)&Bs[r][kb + j * 8] = wp8[j];
    __syncthreads();

#pragma unroll
    for (int kk = 0; kk < 2; kk++) {
      short8 a[4], b[4];
#pragma unroll
      for (int mt = 0; mt < 4; mt++)
        a[mt] = *(const short8*)&As[moff + mt * 16 + (lane & 15)][kk * 32 + (lane >> 4) * 8];
#pragma unroll
      for (int nt = 0; nt < 4; nt++)
        b[nt] = *(const short8*)&Bs[noff + nt * 16 + (lane & 15)][kk * 32 + (lane >> 4) * 8];
#pragma unroll
      for (int mt = 0; mt < 4; mt++)
#pragma unroll
        for (int nt = 0; nt < 4; nt++)
          acc[mt][nt] = __builtin_amdgcn_mfma_f32_16x16x32_bf16(a[mt], b[nt], acc[mt][nt], 0, 0, 0);
    }
    __syncthreads();
  }

#pragma unroll
  for (int nt = 0; nt < 4; nt++) {
    const int cg = bn * 128 + noff + nt * 16 + (lane & 15);
    const float bi = bias[cg];
#pragma unroll
    for (int mt = 0; mt < 4; mt++) {
      const int rg2 = bm * 128 + moff + mt * 16 + (lane >> 4) * 4;
#pragma unroll
      for (int i = 0; i < 4; i++)
        XM[(size_t)(rg2 + i) * 1536 + cg] = f2bf(acc[mt][nt][i] + bi);
    }
  }
}

// ---------------- Phase 2: recurrence, sentinel + tagged bulk exchange ----------------
// 32 blocks x 256 threads; pure dataflow coupling (no barriers, no flags).
// Ring word [slot=t&1][batch][unitpair]: u64 {hi32=t+1, lo32=bf16(u)|bf16(u+1)<<16}.
// Producer block p writes unit pairs [8p, 8p+8) of every batch row.
// Consumer lane (col,krow) of wave w reads row w*16+col, words krow*4+ks*16+{0..3}.
__global__ __launch_bounds__(256, 1) void gru_rec(const unsigned short* __restrict__ Rt,
                                                  const unsigned short* __restrict__ XM,
                                                  const float* __restrict__ bias,
                                                  unsigned long long* ring,
                                                  float* __restrict__ out) {
  const int tid = threadIdx.x;
  const int lane = tid & 63;
  const int wave = tid >> 6;          // 0..3 -> batches wave*16..+15
  const int blk = blockIdx.x;         // 0..31 -> units blk*16..+15
  const int u0 = blk * 16;
  const int col = lane & 15;
  const int krow = lane >> 4;         // 0..3

  // B fragments: Rt[g*512+u0+col][k], k = ks*32 + krow*8 + j
  short8 Bf[3][16];
#pragma unroll
  for (int g = 0; g < 3; g++)
#pragma unroll
    for (int ks = 0; ks < 16; ks++)
      Bf[g][ks] = *(const short8*)(Rt + (size_t)(g * 512 + u0 + col) * 512 + ks * 32 + krow * 8);

  const float br0 = bias[1536 + 0 * 512 + u0 + col];
  const float br1 = bias[1536 + 1 * 512 + u0 + col];
  const float br2 = bias[1536 + 2 * 512 + u0 + col];

  float hreg[4] = {0.f, 0.f, 0.f, 0.f};

  unsigned short xc[3][4], xn[3][4];
#pragma unroll
  for (int g = 0; g < 3; g++)
#pragma unroll
    for (int i = 0; i < 4; i++) {
      int batch = wave * 16 + krow * 4 + i;
      xc[g][i] = XM[(size_t)batch * 1536 + g * 512 + u0 + col];
    }

  // sentinel address component: lane p<32 polls producer p's FIRST-stored word
  // (i=0 store: row w*16+(p&3)*4, word position p*8) in this wave's batch group.
  const int sp_p = lane & 31;
  const size_t sp_off = (size_t)(wave * 16 + (sp_p & 3) * 4) * 256 + (size_t)sp_p * 8;

#pragma unroll 1
  for (int t = 0; t < 1024; ++t) {
    f32x4 acc0 = (f32x4){0.f, 0.f, 0.f, 0.f};
    f32x4 acc1 = acc0, acc2 = acc0;
    const int tn = (t < 1023) ? t + 1 : 1023;

    if (t > 0) {
      const unsigned tagv = (unsigned)t;
      const size_t slotbase = (size_t)((t + 1) & 1) * 16384;
      const unsigned long long* hp =
          ring + slotbase + (size_t)(wave * 16 + col) * 256 + krow * 4;
      const unsigned long long* sp = ring + slotbase + sp_off;
      short8 Af[16];

      // ---- sentinel poll: 1 word per producer (32 loads/wave/poll) ----
      for (;;) {
        unsigned long long s = __hip_atomic_load(sp, __ATOMIC_RELAXED,
                                                 __HIP_MEMORY_SCOPE_AGENT);
        if (__all((int)((unsigned)(s >> 32) == tagv))) break;
        __builtin_amdgcn_s_sleep(1);
      }

      // ---- bulk slice load + full tag validation (bounded cheap retries) ----
      for (;;) {
        unsigned bad = 0;
#pragma unroll
        for (int ks = 0; ks < 16; ++ks) {
          unsigned long long a0 = __hip_atomic_load(hp + ks * 16 + 0, __ATOMIC_RELAXED,
                                                    __HIP_MEMORY_SCOPE_AGENT);
          unsigned long long a1 = __hip_atomic_load(hp + ks * 16 + 1, __ATOMIC_RELAXED,
                                                    __HIP_MEMORY_SCOPE_AGENT);
          unsigned long long a2 = __hip_atomic_load(hp + ks * 16 + 2, __ATOMIC_RELAXED,
                                                    __HIP_MEMORY_SCOPE_AGENT);
          unsigned long long a3 = __hip_atomic_load(hp + ks * 16 + 3, __ATOMIC_RELAXED,
                                                    __HIP_MEMORY_SCOPE_AGENT);
          bad |= (((unsigned)(a0 >> 32)) ^ tagv) | (((unsigned)(a1 >> 32)) ^ tagv) |
                 (((unsigned)(a2 >> 32)) ^ tagv) | (((unsigned)(a3 >> 32)) ^ tagv);
          u32x4 d = (u32x4){(unsigned)a0, (unsigned)a1, (unsigned)a2, (unsigned)a3};
          Af[ks] = __builtin_bit_cast(short8, d);
        }
        if (__all((int)(bad == 0))) break;
        __builtin_amdgcn_s_sleep(1);
      }

      // XM prefetch for t+1 (hides under MFMA)
#pragma unroll
      for (int g = 0; g < 3; g++)
#pragma unroll
        for (int i = 0; i < 4; i++) {
          int batch = wave * 16 + krow * 4 + i;
          xn[g][i] = XM[(size_t)(tn * 64 + batch) * 1536 + g * 512 + u0 + col];
        }

#pragma unroll
      for (int ks = 0; ks < 16; ++ks) {
        acc0 = __builtin_amdgcn_mfma_f32_16x16x32_bf16(Af[ks], Bf[0][ks], acc0, 0, 0, 0);
        acc1 = __builtin_amdgcn_mfma_f32_16x16x32_bf16(Af[ks], Bf[1][ks], acc1, 0, 0, 0);
        acc2 = __builtin_amdgcn_mfma_f32_16x16x32_bf16(Af[ks], Bf[2][ks], acc2, 0, 0, 0);
      }
    } else {
#pragma unroll
      for (int g = 0; g < 3; g++)
#pragma unroll
        for (int i = 0; i < 4; i++) {
          int batch = wave * 16 + krow * 4 + i;
          xn[g][i] = XM[(size_t)(tn * 64 + batch) * 1536 + g * 512 + u0 + col];
        }
    }

    // gates (fp32); identical arithmetic since r2.
#pragma unroll
    for (int i = 0; i < 4; i++) {
      float hz = acc0[i] + br0;
      float hr = acc1[i] + br1;
      float hh = acc2[i] + br2;
      float xz = bf2f(xc[0][i]);
      float xr = bf2f(xc[1][i]);
      float xh = bf2f(xc[2][i]);
      float z = 1.f / (1.f + __expf(-(xz + hz)));
      float r = 1.f / (1.f + __expf(-(xr + hr)));
      float y = xh + r * hh;
      float ay = fabsf(y);
      float e = __expf(-2.f * ay);
      float ca = (1.f - e) / (1.f + e);          // |tanh|
      ca = (y < 0.f) ? -ca : ca;
      hreg[i] = z * hreg[i] + (1.f - z) * ca;
    }

    if (t < 1023) {
      // producer: tagged u64 stores, relaxed agent. Nothing else -- the tag is
      // the publication. Depth-2 overwrite safety: storing h_{t+1} requires
      // having validated everyone's h_t, which required their h_{t-1} loads done.
      const size_t sb = (size_t)(t & 1) * 16384;
      const unsigned long long tagbits = ((unsigned long long)(unsigned)(t + 1)) << 32;
#pragma unroll
      for (int i = 0; i < 4; i++) {
        int batch = wave * 16 + krow * 4 + i;
        float other = __shfl_xor(hreg[i], 1);
        if ((col & 1) == 0) {
          unsigned d = (unsigned)f2bf(hreg[i]) | ((unsigned)f2bf(other) << 16);
          __hip_atomic_store(ring + sb + (size_t)batch * 256 + ((u0 + col) >> 1),
                             tagbits | (unsigned long long)d,
                             __ATOMIC_RELAXED, __HIP_MEMORY_SCOPE_AGENT);
        }
      }
    }

#pragma unroll
    for (int g = 0; g < 3; g++)
#pragma unroll
      for (int i = 0; i < 4; i++) xc[g][i] = xn[g][i];
  }

#pragma unroll
  for (int i = 0; i < 4; i++) {
    int batch = wave * 16 + krow * 4 + i;
    out[(size_t)batch * 512 + u0 + col] = hreg[i];
  }
}

// ---------------- launch ----------------
extern "C" void kernel_launch(void* const* d_in, const int* in_sizes, int n_in,
                              void* d_out, int out_size, void* d_ws, size_t ws_size,
                              hipStream_t stream) {
  const float* x = (const float*)d_in[0];       // [64][1024][512]
  const float* W = (const float*)d_in[1];       // [512][1536]
  const float* R = (const float*)d_in[2];       // [512][1536]
  const float* bias = (const float*)d_in[3];    // [2][1536]
  float* out = (float*)d_out;

  char* ws = (char*)d_ws;
  unsigned short* Wt = (unsigned short*)(ws + 135168);
  unsigned long long* ring = (unsigned long long*)(ws + 135168);  // overlays Wt
  unsigned short* Rt = (unsigned short*)(ws + 1708032);
  unsigned short* XM = (unsigned short*)(ws + 3280896);

  transpose_cast<<<dim3(48, 16), dim3(32, 8), 0, stream>>>(W, Wt, 512, 1536);
  transpose_cast<<<dim3(48, 16), dim3(32, 8), 0, stream>>>(R, Rt, 512, 1536);
  xm_gemm<<<dim3(512, 12), dim3(256), 0, stream>>>(x, Wt, bias, XM);
  // Wt dead now; zero the tagged ring (tag 0 matches no step t in [1,1024]).
  hipMemsetAsync(ring, 0, 2ull * 64 * 256 * 8, stream);
  gru_rec<<<dim3(32), dim3(256), 0, stream>>>(Rt, XM, bias, ring, out);
}

// Round 11
// 4437.222 us; speedup vs baseline: 6.1491x; 2.2366x over previous
//
#include <hip/hip_runtime.h>
#include <hip/hip_bf16.h>

// GRU B=64 T=1024 D=U=512, reset_after=true. fp32 in/out, bf16 MFMA internally.
//
// Phase 2 v9: r5's proven drain->flag->poll protocol, repartitioned.
// 32 blocks = 4 batch-groups (i) x 8 unit-groups (j). Block(i,j): batches
// [16i,+16), units [64j,+64). Exchange is PER GROUP (8 blocks): 4x fewer
// atomic loads (block stages its 16KB h slice into LDS once; waves read
// fragments from LDS), rendezvous width 8, groups fully decoupled.
//
// ws layout (bytes):
//   [0,512)                  flags u32[4 groups][32] (memset at launch)
//   [135168, +131072)        h rings u32[4][2][16][256] (overlay dead Wt)
//   [135168, +1572864)       Wt  bf16 [1536][512]  (dead after xm_gemm)
//   [1708032, +1572864)      Rt  bf16 [1536][512]
//   [3280896, +201326592)    XM  bf16 [T*64][1536] (x@W + b_i), row = t*64+b

typedef __attribute__((ext_vector_type(8))) short short8;
typedef __attribute__((ext_vector_type(4))) float f32x4;
typedef __attribute__((ext_vector_type(4))) unsigned int u32x4;

__device__ __forceinline__ unsigned short f2bf(float f) {
  unsigned u = __float_as_uint(f);
  u += 0x7FFFu + ((u >> 16) & 1u);   // RNE
  return (unsigned short)(u >> 16);
}
__device__ __forceinline__ float bf2f(unsigned short s) {
  return __uint_as_float(((unsigned)s) << 16);
}

// ---------------- Phase 0: transpose fp32 [R][C] -> bf16 [C][R] ----------------
__global__ void transpose_cast(const float* __restrict__ src,
                               unsigned short* __restrict__ dst,
                               int R, int C) {
  __shared__ float tile[32][33];
  int c0 = blockIdx.x * 32, r0 = blockIdx.y * 32;
  int tx = threadIdx.x, ty = threadIdx.y;
#pragma unroll
  for (int i = 0; i < 4; i++) {
    tile[ty + i * 8][tx] = src[(size_t)(r0 + ty + i * 8) * C + c0 + tx];
  }
  __syncthreads();
#pragma unroll
  for (int i = 0; i < 4; i++) {
    dst[(size_t)(c0 + ty + i * 8) * R + r0 + tx] = f2bf(tile[tx][ty + i * 8]);
  }
}

// ---------------- Phase 1: XM = x @ W + b_i  (bf16 out) ----------------
__global__ __launch_bounds__(256) void xm_gemm(const float* __restrict__ x,
                                               const unsigned short* __restrict__ Wt,
                                               const float* __restrict__ bias,
                                               unsigned short* __restrict__ XM) {
  __shared__ unsigned short As[128][72];
  __shared__ unsigned short Bs[128][72];
  const int tid = threadIdx.x;
  const int bm = blockIdx.x;   // 512
  const int bn = blockIdx.y;   // 12
  const int wave = tid >> 6, lane = tid & 63;
  const int moff = (wave & 1) * 64, noff = (wave >> 1) * 64;

  f32x4 acc[4][4];
#pragma unroll
  for (int mt = 0; mt < 4; mt++)
#pragma unroll
    for (int nt = 0; nt < 4; nt++) acc[mt][nt] = (f32x4){0.f, 0.f, 0.f, 0.f};

  const int r = tid >> 1;
  const int kb = (tid & 1) * 32;
  const int rg = bm * 128 + r;
  const int bb = rg & 63, tt = rg >> 6;

  for (int k0 = 0; k0 < 512; k0 += 64) {
    const f32x4* xp4 = (const f32x4*)(x + ((size_t)bb * 1024 + tt) * 512 + k0 + kb);
#pragma unroll
    for (int j = 0; j < 4; j++) {
      f32x4 lo = xp4[2 * j];
      f32x4 hi = xp4[2 * j + 1];
      union { unsigned short us[8]; short8 v; } u;
      u.us[0] = f2bf(lo[0]); u.us[1] = f2bf(lo[1]); u.us[2] = f2bf(lo[2]); u.us[3] = f2bf(lo[3]);
      u.us[4] = f2bf(hi[0]); u.us[5] = f2bf(hi[1]); u.us[6] = f2bf(hi[2]); u.us[7] = f2bf(hi[3]);
      *(short8*)&As[r][kb + j * 8] = u.v;
    }
    const short8* wp8 = (const short8*)(Wt + (size_t)(bn * 128 + r) * 512 + k0 + kb);
#pragma unroll
    for (int j = 0; j < 4; j++) *(short8*)&Bs[r][kb + j * 8] = wp8[j];
    __syncthreads();

#pragma unroll
    for (int kk = 0; kk < 2; kk++) {
      short8 a[4], b[4];
#pragma unroll
      for (int mt = 0; mt < 4; mt++)
        a[mt] = *(const short8*)&As[moff + mt * 16 + (lane & 15)][kk * 32 + (lane >> 4) * 8];
#pragma unroll
      for (int nt = 0; nt < 4; nt++)
        b[nt] = *(const short8*)&Bs[noff + nt * 16 + (lane & 15)][kk * 32 + (lane >> 4) * 8];
#pragma unroll
      for (int mt = 0; mt < 4; mt++)
#pragma unroll
        for (int nt = 0; nt < 4; nt++)
          acc[mt][nt] = __builtin_amdgcn_mfma_f32_16x16x32_bf16(a[mt], b[nt], acc[mt][nt], 0, 0, 0);
    }
    __syncthreads();
  }

#pragma unroll
  for (int nt = 0; nt < 4; nt++) {
    const int cg = bn * 128 + noff + nt * 16 + (lane & 15);
    const float bi = bias[cg];
#pragma unroll
    for (int mt = 0; mt < 4; mt++) {
      const int rg2 = bm * 128 + moff + mt * 16 + (lane >> 4) * 4;
#pragma unroll
      for (int i = 0; i < 4; i++)
        XM[(size_t)(rg2 + i) * 1536 + cg] = f2bf(acc[mt][nt][i] + bi);
    }
  }
}

// ---------------- Phase 2: recurrence, grouped r5 protocol + LDS staging ----------------
__global__ __launch_bounds__(256, 1) void gru_rec(const unsigned short* __restrict__ Rt,
                                                  const unsigned short* __restrict__ XM,
                                                  const float* __restrict__ bias,
                                                  unsigned int* ring,
                                                  unsigned int* flags,
                                                  float* __restrict__ out) {
  const int tid = threadIdx.x;
  const int lane = tid & 63;
  const int w = tid >> 6;             // wave 0..3
  const int blk = blockIdx.x;
  const int gi = blk >> 3;            // batch group: batches [16gi, +16)
  const int j = blk & 7;              // unit group:  units   [64j, +64)
  const int B0 = gi * 16;
  const int u0 = j * 64 + w * 16;     // this wave's 16-unit slice
  const int col = lane & 15;
  const int krow = lane >> 4;         // 0..3

  unsigned int* ring_g = ring + (size_t)gi * 8192;          // u32[2][16][256]
  unsigned long long* ring64_g = (unsigned long long*)ring_g; // u64[2][16][128]
  unsigned int* flg = flags + gi * 32;

  __shared__ unsigned short hlds[16][520];   // [local batch][512 units + 8 pad]

  // weights: Bf[gate][ks] = Rt[gate*512+u0+col][ks*32+krow*8 ..+8]
  short8 Bf[3][16];
#pragma unroll
  for (int g3 = 0; g3 < 3; g3++)
#pragma unroll
    for (int ks = 0; ks < 16; ks++)
      Bf[g3][ks] = *(const short8*)(Rt + (size_t)(g3 * 512 + u0 + col) * 512 + ks * 32 + krow * 8);

  const float br0 = bias[1536 + 0 * 512 + u0 + col];
  const float br1 = bias[1536 + 1 * 512 + u0 + col];
  const float br2 = bias[1536 + 2 * 512 + u0 + col];

  float hreg[4] = {0.f, 0.f, 0.f, 0.f};

  // staging ids: thread loads 64B of the group's 16KB slice
  const int rb = tid >> 4;            // local batch row 0..15
  const int cu = tid & 15;            // 32-unit chunk 0..15

  unsigned short xc[3][4], xn[3][4];
#pragma unroll
  for (int g3 = 0; g3 < 3; g3++)
#pragma unroll
    for (int i = 0; i < 4; i++) {
      int batch = B0 + krow * 4 + i;
      xc[g3][i] = XM[(size_t)batch * 1536 + g3 * 512 + u0 + col];
    }

#pragma unroll 1
  for (int t = 0; t < 1024; ++t) {
    f32x4 acc0 = (f32x4){0.f, 0.f, 0.f, 0.f};
    f32x4 acc1 = acc0, acc2 = acc0;
    const int tn = (t < 1023) ? t + 1 : 1023;

    if (t > 0) {
      // ---- detect: wave0 polls this group's 8 flags ----
      if (w == 0) {
        const unsigned tgt = (unsigned)t;
        for (;;) {
          unsigned v = (lane < 8)
              ? __hip_atomic_load(&flg[lane], __ATOMIC_RELAXED, __HIP_MEMORY_SCOPE_AGENT)
              : tgt;
          if (__all((int)(v >= tgt))) break;
          __builtin_amdgcn_s_sleep(1);
        }
      }
      __syncthreads();

      // ---- cooperative 16KB slice load (8 u64 atomics/thread) ----
      const unsigned long long* rp =
          ring64_g + (size_t)((t + 1) & 1) * 2048 + (size_t)rb * 128 + (size_t)cu * 8;
      unsigned long long q[8];
#pragma unroll
      for (int k = 0; k < 8; ++k)
        q[k] = __hip_atomic_load(rp + k, __ATOMIC_RELAXED, __HIP_MEMORY_SCOPE_AGENT);

      // XM prefetch for t+1 (in flight alongside staging)
#pragma unroll
      for (int g3 = 0; g3 < 3; g3++)
#pragma unroll
        for (int i = 0; i < 4; i++) {
          int batch = B0 + krow * 4 + i;
          xn[g3][i] = XM[(size_t)(tn * 64 + batch) * 1536 + g3 * 512 + u0 + col];
        }

      // ---- LDS write (4 x 16B) ----
      u32x4* dst = (u32x4*)&hlds[rb][cu * 32];
#pragma unroll
      for (int k = 0; k < 4; ++k)
        dst[k] = (u32x4){(unsigned)q[2 * k], (unsigned)(q[2 * k] >> 32),
                         (unsigned)q[2 * k + 1], (unsigned)(q[2 * k + 1] >> 32)};
      __syncthreads();

      // ---- fragments from LDS + MFMA ----
      short8 Af[16];
#pragma unroll
      for (int ks = 0; ks < 16; ++ks)
        Af[ks] = *(const short8*)&hlds[col][ks * 32 + krow * 8];
#pragma unroll
      for (int ks = 0; ks < 16; ++ks) {
        acc0 = __builtin_amdgcn_mfma_f32_16x16x32_bf16(Af[ks], Bf[0][ks], acc0, 0, 0, 0);
        acc1 = __builtin_amdgcn_mfma_f32_16x16x32_bf16(Af[ks], Bf[1][ks], acc1, 0, 0, 0);
        acc2 = __builtin_amdgcn_mfma_f32_16x16x32_bf16(Af[ks], Bf[2][ks], acc2, 0, 0, 0);
      }
    } else {
#pragma unroll
      for (int g3 = 0; g3 < 3; g3++)
#pragma unroll
        for (int i = 0; i < 4; i++) {
          int batch = B0 + krow * 4 + i;
          xn[g3][i] = XM[(size_t)(tn * 64 + batch) * 1536 + g3 * 512 + u0 + col];
        }
    }

    // gates (fp32); identical arithmetic since r2.
#pragma unroll
    for (int i = 0; i < 4; i++) {
      float hz = acc0[i] + br0;
      float hr = acc1[i] + br1;
      float hh = acc2[i] + br2;
      float xz = bf2f(xc[0][i]);
      float xr = bf2f(xc[1][i]);
      float xh = bf2f(xc[2][i]);
      float z = 1.f / (1.f + __expf(-(xz + hz)));
      float r = 1.f / (1.f + __expf(-(xr + hr)));
      float y = xh + r * hh;
      float ay = fabsf(y);
      float e = __expf(-2.f * ay);
      float ca = (1.f - e) / (1.f + e);          // |tanh|
      ca = (y < 0.f) ? -ca : ca;
      hreg[i] = z * hreg[i] + (1.f - z) * ca;
    }

    if (t < 1023) {
      // producer: r5-proven chain. relaxed u32 stores -> vmcnt drain ->
      // block barrier -> tid0 publishes this block's flag.
      unsigned int* hw = ring_g + (size_t)(t & 1) * 4096;
#pragma unroll
      for (int i = 0; i < 4; i++) {
        int lb = krow * 4 + i;              // local batch 0..15
        float other = __shfl_xor(hreg[i], 1);
        if ((col & 1) == 0) {
          unsigned d = (unsigned)f2bf(hreg[i]) | ((unsigned)f2bf(other) << 16);
          __hip_atomic_store(hw + (size_t)lb * 256 + ((u0 + col) >> 1), d,
                             __ATOMIC_RELAXED, __HIP_MEMORY_SCOPE_AGENT);
        }
      }
      asm volatile("s_waitcnt vmcnt(0)" ::: "memory");
      __syncthreads();
      if (tid == 0) {
        __hip_atomic_store(&flg[j], (unsigned)(t + 1),
                           __ATOMIC_RELAXED, __HIP_MEMORY_SCOPE_AGENT);
      }
    }

#pragma unroll
    for (int g3 = 0; g3 < 3; g3++)
#pragma unroll
      for (int i = 0; i < 4; i++) xc[g3][i] = xn[g3][i];
  }

#pragma unroll
  for (int i = 0; i < 4; i++) {
    int batch = B0 + krow * 4 + i;
    out[(size_t)batch * 512 + u0 + col] = hreg[i];
  }
}

// ---------------- launch ----------------
extern "C" void kernel_launch(void* const* d_in, const int* in_sizes, int n_in,
                              void* d_out, int out_size, void* d_ws, size_t ws_size,
                              hipStream_t stream) {
  const float* x = (const float*)d_in[0];       // [64][1024][512]
  const float* W = (const float*)d_in[1];       // [512][1536]
  const float* R = (const float*)d_in[2];       // [512][1536]
  const float* bias = (const float*)d_in[3];    // [2][1536]
  float* out = (float*)d_out;

  char* ws = (char*)d_ws;
  unsigned int* flags = (unsigned int*)(ws + 0);
  unsigned short* Wt = (unsigned short*)(ws + 135168);
  unsigned int* ring = (unsigned int*)(ws + 135168);   // overlays Wt
  unsigned short* Rt = (unsigned short*)(ws + 1708032);
  unsigned short* XM = (unsigned short*)(ws + 3280896);

  hipMemsetAsync(flags, 0, 4096, stream);
  transpose_cast<<<dim3(48, 16), dim3(32, 8), 0, stream>>>(W, Wt, 512, 1536);
  transpose_cast<<<dim3(48, 16), dim3(32, 8), 0, stream>>>(R, Rt, 512, 1536);
  xm_gemm<<<dim3(512, 12), dim3(256), 0, stream>>>(x, Wt, bias, XM);
  gru_rec<<<dim3(32), dim3(256), 0, stream>>>(Rt, XM, bias, ring, flags, out);
}

// Round 13
// 3469.747 us; speedup vs baseline: 7.8636x; 1.2788x over previous
//
#include <hip/hip_runtime.h>
#include <hip/hip_bf16.h>

// GRU B=64 T=1024 D=U=512, reset_after=true. fp32 in/out, bf16 MFMA internally.
//
// Phase 2 v11: r5-proven drain->flag->poll protocol, 8x8 partition, swizzled LDS.
// 64 blocks = 8 batch-groups (gi) x 8 unit-blocks (j). Block: batches [8gi,+8),
// units [64j,+64). Per-group exchange = 8KB/step through MALL; cooperative
// staging into XOR-swizzled LDS (conflict-free both sides). Weights are plain
// loads (compiler-managed; r12's asm pinning caused stale-register NaNs).
// XM prefetch issued AFTER flag publish so the producer drain covers only the
// 4 h-stores.
//
// ws layout (bytes):
//   [0,1024)                 flags u32[8 groups][32] (memset at launch)
//   [135168, +131072)        h rings u32[8][2][8][256] (overlay dead Wt)
//   [135168, +1572864)       Wt  bf16 [1536][512]  (dead after xm_gemm)
//   [1708032, +1572864)      Rt  bf16 [1536][512]
//   [3280896, +201326592)    XM  bf16 [T*64][1536] (x@W + b_i), row = t*64+b

typedef __attribute__((ext_vector_type(8))) short short8;
typedef __attribute__((ext_vector_type(4))) float f32x4;
typedef __attribute__((ext_vector_type(4))) unsigned int u32x4;

__device__ __forceinline__ unsigned short f2bf(float f) {
  unsigned u = __float_as_uint(f);
  u += 0x7FFFu + ((u >> 16) & 1u);   // RNE
  return (unsigned short)(u >> 16);
}
__device__ __forceinline__ float bf2f(unsigned short s) {
  return __uint_as_float(((unsigned)s) << 16);
}

// ---------------- Phase 0: transpose fp32 [R][C] -> bf16 [C][R] ----------------
__global__ void transpose_cast(const float* __restrict__ src,
                               unsigned short* __restrict__ dst,
                               int R, int C) {
  __shared__ float tile[32][33];
  int c0 = blockIdx.x * 32, r0 = blockIdx.y * 32;
  int tx = threadIdx.x, ty = threadIdx.y;
#pragma unroll
  for (int i = 0; i < 4; i++) {
    tile[ty + i * 8][tx] = src[(size_t)(r0 + ty + i * 8) * C + c0 + tx];
  }
  __syncthreads();
#pragma unroll
  for (int i = 0; i < 4; i++) {
    dst[(size_t)(c0 + ty + i * 8) * R + r0 + tx] = f2bf(tile[tx][ty + i * 8]);
  }
}

// ---------------- Phase 1: XM = x @ W + b_i  (bf16 out) ----------------
__global__ __launch_bounds__(256) void xm_gemm(const float* __restrict__ x,
                                               const unsigned short* __restrict__ Wt,
                                               const float* __restrict__ bias,
                                               unsigned short* __restrict__ XM) {
  __shared__ unsigned short As[128][72];
  __shared__ unsigned short Bs[128][72];
  const int tid = threadIdx.x;
  const int bm = blockIdx.x;   // 512
  const int bn = blockIdx.y;   // 12
  const int wave = tid >> 6, lane = tid & 63;
  const int moff = (wave & 1) * 64, noff = (wave >> 1) * 64;

  f32x4 acc[4][4];
#pragma unroll
  for (int mt = 0; mt < 4; mt++)
#pragma unroll
    for (int nt = 0; nt < 4; nt++) acc[mt][nt] = (f32x4){0.f, 0.f, 0.f, 0.f};

  const int r = tid >> 1;
  const int kb = (tid & 1) * 32;
  const int rg = bm * 128 + r;
  const int bb = rg & 63, tt = rg >> 6;

  for (int k0 = 0; k0 < 512; k0 += 64) {
    const f32x4* xp4 = (const f32x4*)(x + ((size_t)bb * 1024 + tt) * 512 + k0 + kb);
#pragma unroll
    for (int j = 0; j < 4; j++) {
      f32x4 lo = xp4[2 * j];
      f32x4 hi = xp4[2 * j + 1];
      union { unsigned short us[8]; short8 v; } u;
      u.us[0] = f2bf(lo[0]); u.us[1] = f2bf(lo[1]); u.us[2] = f2bf(lo[2]); u.us[3] = f2bf(lo[3]);
      u.us[4] = f2bf(hi[0]); u.us[5] = f2bf(hi[1]); u.us[6] = f2bf(hi[2]); u.us[7] = f2bf(hi[3]);
      *(short8*)&As[r][kb + j * 8] = u.v;
    }
    const short8* wp8 = (const short8*)(Wt + (size_t)(bn * 128 + r) * 512 + k0 + kb);
#pragma unroll
    for (int j = 0; j < 4; j++) *(short8*)&Bs[r][kb + j * 8] = wp8[j];
    __syncthreads();

#pragma unroll
    for (int kk = 0; kk < 2; kk++) {
      short8 a[4], b[4];
#pragma unroll
      for (int mt = 0; mt < 4; mt++)
        a[mt] = *(const short8*)&As[moff + mt * 16 + (lane & 15)][kk * 32 + (lane >> 4) * 8];
#pragma unroll
      for (int nt = 0; nt < 4; nt++)
        b[nt] = *(const short8*)&Bs[noff + nt * 16 + (lane & 15)][kk * 32 + (lane >> 4) * 8];
#pragma unroll
      for (int mt = 0; mt < 4; mt++)
#pragma unroll
        for (int nt = 0; nt < 4; nt++)
          acc[mt][nt] = __builtin_amdgcn_mfma_f32_16x16x32_bf16(a[mt], b[nt], acc[mt][nt], 0, 0, 0);
    }
    __syncthreads();
  }

#pragma unroll
  for (int nt = 0; nt < 4; nt++) {
    const int cg = bn * 128 + noff + nt * 16 + (lane & 15);
    const float bi = bias[cg];
#pragma unroll
    for (int mt = 0; mt < 4; mt++) {
      const int rg2 = bm * 128 + moff + mt * 16 + (lane >> 4) * 4;
#pragma unroll
      for (int i = 0; i < 4; i++)
        XM[(size_t)(rg2 + i) * 1536 + cg] = f2bf(acc[mt][nt][i] + bi);
    }
  }
}

// ---------------- Phase 2: recurrence, 8x8 groups + swizzled LDS ----------------
__global__ __launch_bounds__(256, 1) void gru_rec(const unsigned short* __restrict__ Rt,
                                                  const unsigned short* __restrict__ XM,
                                                  const float* __restrict__ bias,
                                                  unsigned int* ring,
                                                  unsigned int* flags,
                                                  float* __restrict__ out) {
  const int tid = threadIdx.x;
  const int lane = tid & 63;
  const int w = tid >> 6;             // wave 0..3
  const int blk = blockIdx.x;         // 0..63
  const int gi = blk >> 3;            // batch group: batches [8gi, +8)
  const int j = blk & 7;              // unit block:  units   [64j, +64)
  const int u0 = j * 64 + w * 16;     // this wave's 16-unit slice
  const int col = lane & 15;
  const int krow = lane >> 4;         // 0..3
  const int hrow = col & 7;           // LDS h row this lane's A-frag reads

  unsigned int* ring_g = ring + (size_t)gi * 4096;            // u32[2][8][256]
  unsigned long long* ring64_g = (unsigned long long*)ring_g; // u64[2][1024]
  unsigned int* flg = flags + gi * 32;

  __shared__ alignas(16) unsigned short hlds[8][512];  // XOR-swizzled chunks

  // weights: plain loads, compiler-managed (r11-proven)
  short8 Bf[3][16];
#pragma unroll
  for (int g3 = 0; g3 < 3; g3++)
#pragma unroll
    for (int ks = 0; ks < 16; ks++)
      Bf[g3][ks] = *(const short8*)(Rt + (size_t)(g3 * 512 + u0 + col) * 512 + ks * 32 + krow * 8);

  const float br0 = bias[1536 + 0 * 512 + u0 + col];
  const float br1 = bias[1536 + 1 * 512 + u0 + col];
  const float br2 = bias[1536 + 2 * 512 + u0 + col];

  float hreg[4] = {0.f, 0.f, 0.f, 0.f};

  // coop staging ids: thread loads 16B chunk g1=tid (rows 0..3) and g2=tid+256 (rows 4..7)
  const int g1 = tid, g2 = tid + 256;
  const int r1 = g1 >> 6, c1s = (g1 & 63) ^ r1;
  const int r2 = g2 >> 6, c2s = (g2 & 63) ^ r2;

  unsigned short xc[3][4], xn[3][4];
#pragma unroll
  for (int g3 = 0; g3 < 3; g3++)
#pragma unroll
    for (int i = 0; i < 4; i++) {
      int batch = gi * 8 + ((krow * 4 + i) & 7);
      xc[g3][i] = XM[(size_t)batch * 1536 + g3 * 512 + u0 + col];
    }

#pragma unroll 1
  for (int t = 0; t < 1024; ++t) {
    f32x4 acc0 = (f32x4){0.f, 0.f, 0.f, 0.f};
    f32x4 acc1 = acc0, acc2 = acc0;

    if (t > 0) {
      // ---- detect: wave0 polls this group's 8 flags ----
      if (w == 0) {
        const unsigned tgt = (unsigned)t;
        for (;;) {
          unsigned v = (lane < 8)
              ? __hip_atomic_load(&flg[lane], __ATOMIC_RELAXED, __HIP_MEMORY_SCOPE_AGENT)
              : tgt;
          if (__all((int)(v >= tgt))) break;
          __builtin_amdgcn_s_sleep(1);
        }
      }
      __syncthreads();

      // ---- cooperative 8KB slice load (4 u64 atomics/thread) ----
      const unsigned long long* rp = ring64_g + (size_t)((t + 1) & 1) * 1024;
      unsigned long long qa0 = __hip_atomic_load(rp + 2 * g1, __ATOMIC_RELAXED,
                                                 __HIP_MEMORY_SCOPE_AGENT);
      unsigned long long qa1 = __hip_atomic_load(rp + 2 * g1 + 1, __ATOMIC_RELAXED,
                                                 __HIP_MEMORY_SCOPE_AGENT);
      unsigned long long qb0 = __hip_atomic_load(rp + 2 * g2, __ATOMIC_RELAXED,
                                                 __HIP_MEMORY_SCOPE_AGENT);
      unsigned long long qb1 = __hip_atomic_load(rp + 2 * g2 + 1, __ATOMIC_RELAXED,
                                                 __HIP_MEMORY_SCOPE_AGENT);

      // ---- swizzled LDS write (2 x 16B per thread, conflict-free) ----
      *(u32x4*)&hlds[r1][c1s * 8] =
          (u32x4){(unsigned)qa0, (unsigned)(qa0 >> 32), (unsigned)qa1, (unsigned)(qa1 >> 32)};
      *(u32x4*)&hlds[r2][c2s * 8] =
          (u32x4){(unsigned)qb0, (unsigned)(qb0 >> 32), (unsigned)qb1, (unsigned)(qb1 >> 32)};
      __syncthreads();

      // ---- fragments from LDS (conflict-free) + MFMA ----
      short8 Af[16];
#pragma unroll
      for (int ks = 0; ks < 16; ++ks)
        Af[ks] = *(const short8*)&hlds[hrow][(((ks << 2) + krow) ^ hrow) * 8];
#pragma unroll
      for (int ks = 0; ks < 16; ++ks) {
        acc0 = __builtin_amdgcn_mfma_f32_16x16x32_bf16(Af[ks], Bf[0][ks], acc0, 0, 0, 0);
        acc1 = __builtin_amdgcn_mfma_f32_16x16x32_bf16(Af[ks], Bf[1][ks], acc1, 0, 0, 0);
        acc2 = __builtin_amdgcn_mfma_f32_16x16x32_bf16(Af[ks], Bf[2][ks], acc2, 0, 0, 0);
      }
    }

    // gates (fp32); identical arithmetic since r2. krow>=2 rows are benign dups.
#pragma unroll
    for (int i = 0; i < 4; i++) {
      float hz = acc0[i] + br0;
      float hr = acc1[i] + br1;
      float hh = acc2[i] + br2;
      float xz = bf2f(xc[0][i]);
      float xr = bf2f(xc[1][i]);
      float xh = bf2f(xc[2][i]);
      float z = 1.f / (1.f + __expf(-(xz + hz)));
      float r = 1.f / (1.f + __expf(-(xr + hr)));
      float y = xh + r * hh;
      float ay = fabsf(y);
      float e = __expf(-2.f * ay);
      float ca = (1.f - e) / (1.f + e);          // |tanh|
      ca = (y < 0.f) ? -ca : ca;
      hreg[i] = z * hreg[i] + (1.f - z) * ca;
    }

    if (t < 1023) {
      // producer: r5-proven chain (relaxed stores -> drain -> barrier -> flag).
      // Only the 4 h-stores are outstanding here (XM prefetch comes after),
      // so the vmcnt(0) drain is short.
      unsigned int* hw = ring_g + (size_t)(t & 1) * 2048;
#pragma unroll
      for (int i = 0; i < 4; i++) {
        int lb = krow * 4 + i;              // local batch; valid when krow<2
        float other = __shfl_xor(hreg[i], 1);
        if (krow < 2 && (col & 1) == 0) {
          unsigned d = (unsigned)f2bf(hreg[i]) | ((unsigned)f2bf(other) << 16);
          __hip_atomic_store(hw + (size_t)lb * 256 + ((u0 + col) >> 1), d,
                             __ATOMIC_RELAXED, __HIP_MEMORY_SCOPE_AGENT);
        }
      }
      asm volatile("s_waitcnt vmcnt(0)" ::: "memory");
      __syncthreads();
      if (tid == 0) {
        __hip_atomic_store(&flg[j], (unsigned)(t + 1),
                           __ATOMIC_RELAXED, __HIP_MEMORY_SCOPE_AGENT);
      }
    }

    // XM prefetch for t+1, issued after the flag publish (off the drain path)
    const int tn = (t < 1023) ? t + 1 : 1023;
#pragma unroll
    for (int g3 = 0; g3 < 3; g3++)
#pragma unroll
      for (int i = 0; i < 4; i++) {
        int batch = gi * 8 + ((krow * 4 + i) & 7);
        xn[g3][i] = XM[(size_t)(tn * 64 + batch) * 1536 + g3 * 512 + u0 + col];
      }
#pragma unroll
    for (int g3 = 0; g3 < 3; g3++)
#pragma unroll
      for (int i = 0; i < 4; i++) xc[g3][i] = xn[g3][i];
  }

  if (krow < 2) {
#pragma unroll
    for (int i = 0; i < 4; i++)
      out[(size_t)(gi * 8 + krow * 4 + i) * 512 + u0 + col] = hreg[i];
  }
}

// ---------------- launch ----------------
extern "C" void kernel_launch(void* const* d_in, const int* in_sizes, int n_in,
                              void* d_out, int out_size, void* d_ws, size_t ws_size,
                              hipStream_t stream) {
  const float* x = (const float*)d_in[0];       // [64][1024][512]
  const float* W = (const float*)d_in[1];       // [512][1536]
  const float* R = (const float*)d_in[2];       // [512][1536]
  const float* bias = (const float*)d_in[3];    // [2][1536]
  float* out = (float*)d_out;

  char* ws = (char*)d_ws;
  unsigned int* flags = (unsigned int*)(ws + 0);
  unsigned short* Wt = (unsigned short*)(ws + 135168);
  unsigned int* ring = (unsigned int*)(ws + 135168);   // overlays Wt
  unsigned short* Rt = (unsigned short*)(ws + 1708032);
  unsigned short* XM = (unsigned short*)(ws + 3280896);

  hipMemsetAsync(flags, 0, 4096, stream);
  transpose_cast<<<dim3(48, 16), dim3(32, 8), 0, stream>>>(W, Wt, 512, 1536);
  transpose_cast<<<dim3(48, 16), dim3(32, 8), 0, stream>>>(R, Rt, 512, 1536);
  xm_gemm<<<dim3(512, 12), dim3(256), 0, stream>>>(x, Wt, bias, XM);
  gru_rec<<<dim3(64), dim3(256), 0, stream>>>(Rt, XM, bias, ring, flags, out);
}

// Round 14
// 3018.850 us; speedup vs baseline: 9.0381x; 1.1494x over previous
//
#include <hip/hip_runtime.h>
#include <hip/hip_bf16.h>

// GRU B=64 T=1024 D=U=512, reset_after=true. fp32 in/out, bf16 MFMA internally.
//
// Phase 2 v12: grouped TAGGED ring (flag fused into data).
// 64 blocks = 8 batch-groups (gi) x 8 unit-blocks (j). Block: batches [8gi,+8),
// units [64j,+64). Ring word [group][slot=t&1][batch][unitpair]:
//   u64 {hi32 = step+1, lo32 = bf16(u)|bf16(u+1)<<16}.
// Producer: tagged relaxed-agent stores only (no drain/barrier/flag).
// Consumer: cooperative 64B/thread tagged load; the load IS the poll (retry
// until all 8 own tags == t). Depth-2 overwrite safety by dataflow induction
// (r8-proven); width-8 groups + tiny retry unit remove r8's storm fuel.
//
// ws layout (bytes):
//   [135168, +262144)        ring u64[8][2][8][256] (overlays dead Wt; memset)
//   [135168, +1572864)       Wt  bf16 [1536][512]  (dead after xm_gemm)
//   [1708032, +1572864)      Rt  bf16 [1536][512]
//   [3280896, +201326592)    XM  bf16 [T*64][1536] (x@W + b_i), row = t*64+b

typedef __attribute__((ext_vector_type(8))) short short8;
typedef __attribute__((ext_vector_type(4))) float f32x4;
typedef __attribute__((ext_vector_type(4))) unsigned int u32x4;

__device__ __forceinline__ unsigned short f2bf(float f) {
  unsigned u = __float_as_uint(f);
  u += 0x7FFFu + ((u >> 16) & 1u);   // RNE
  return (unsigned short)(u >> 16);
}
__device__ __forceinline__ float bf2f(unsigned short s) {
  return __uint_as_float(((unsigned)s) << 16);
}

// ---------------- Phase 0: transpose fp32 [R][C] -> bf16 [C][R] ----------------
__global__ void transpose_cast(const float* __restrict__ src,
                               unsigned short* __restrict__ dst,
                               int R, int C) {
  __shared__ float tile[32][33];
  int c0 = blockIdx.x * 32, r0 = blockIdx.y * 32;
  int tx = threadIdx.x, ty = threadIdx.y;
#pragma unroll
  for (int i = 0; i < 4; i++) {
    tile[ty + i * 8][tx] = src[(size_t)(r0 + ty + i * 8) * C + c0 + tx];
  }
  __syncthreads();
#pragma unroll
  for (int i = 0; i < 4; i++) {
    dst[(size_t)(c0 + ty + i * 8) * R + r0 + tx] = f2bf(tile[tx][ty + i * 8]);
  }
}

// ---------------- Phase 1: XM = x @ W + b_i  (bf16 out) ----------------
__global__ __launch_bounds__(256) void xm_gemm(const float* __restrict__ x,
                                               const unsigned short* __restrict__ Wt,
                                               const float* __restrict__ bias,
                                               unsigned short* __restrict__ XM) {
  __shared__ unsigned short As[128][72];
  __shared__ unsigned short Bs[128][72];
  const int tid = threadIdx.x;
  const int bm = blockIdx.x;   // 512
  const int bn = blockIdx.y;   // 12
  const int wave = tid >> 6, lane = tid & 63;
  const int moff = (wave & 1) * 64, noff = (wave >> 1) * 64;

  f32x4 acc[4][4];
#pragma unroll
  for (int mt = 0; mt < 4; mt++)
#pragma unroll
    for (int nt = 0; nt < 4; nt++) acc[mt][nt] = (f32x4){0.f, 0.f, 0.f, 0.f};

  const int r = tid >> 1;
  const int kb = (tid & 1) * 32;
  const int rg = bm * 128 + r;
  const int bb = rg & 63, tt = rg >> 6;

  for (int k0 = 0; k0 < 512; k0 += 64) {
    const f32x4* xp4 = (const f32x4*)(x + ((size_t)bb * 1024 + tt) * 512 + k0 + kb);
#pragma unroll
    for (int j = 0; j < 4; j++) {
      f32x4 lo = xp4[2 * j];
      f32x4 hi = xp4[2 * j + 1];
      union { unsigned short us[8]; short8 v; } u;
      u.us[0] = f2bf(lo[0]); u.us[1] = f2bf(lo[1]); u.us[2] = f2bf(lo[2]); u.us[3] = f2bf(lo[3]);
      u.us[4] = f2bf(hi[0]); u.us[5] = f2bf(hi[1]); u.us[6] = f2bf(hi[2]); u.us[7] = f2bf(hi[3]);
      *(short8*)&As[r][kb + j * 8] = u.v;
    }
    const short8* wp8 = (const short8*)(Wt + (size_t)(bn * 128 + r) * 512 + k0 + kb);
#pragma unroll
    for (int j = 0; j < 4; j++) *(short8*)&Bs[r][kb + j * 8] = wp8[j];
    __syncthreads();

#pragma unroll
    for (int kk = 0; kk < 2; kk++) {
      short8 a[4], b[4];
#pragma unroll
      for (int mt = 0; mt < 4; mt++)
        a[mt] = *(const short8*)&As[moff + mt * 16 + (lane & 15)][kk * 32 + (lane >> 4) * 8];
#pragma unroll
      for (int nt = 0; nt < 4; nt++)
        b[nt] = *(const short8*)&Bs[noff + nt * 16 + (lane & 15)][kk * 32 + (lane >> 4) * 8];
#pragma unroll
      for (int mt = 0; mt < 4; mt++)
#pragma unroll
        for (int nt = 0; nt < 4; nt++)
          acc[mt][nt] = __builtin_amdgcn_mfma_f32_16x16x32_bf16(a[mt], b[nt], acc[mt][nt], 0, 0, 0);
    }
    __syncthreads();
  }

#pragma unroll
  for (int nt = 0; nt < 4; nt++) {
    const int cg = bn * 128 + noff + nt * 16 + (lane & 15);
    const float bi = bias[cg];
#pragma unroll
    for (int mt = 0; mt < 4; mt++) {
      const int rg2 = bm * 128 + moff + mt * 16 + (lane >> 4) * 4;
#pragma unroll
      for (int i = 0; i < 4; i++)
        XM[(size_t)(rg2 + i) * 1536 + cg] = f2bf(acc[mt][nt][i] + bi);
    }
  }
}

// ---------------- Phase 2: recurrence, grouped tagged ring + swizzled LDS ----------------
__global__ __launch_bounds__(256, 1) void gru_rec(const unsigned short* __restrict__ Rt,
                                                  const unsigned short* __restrict__ XM,
                                                  const float* __restrict__ bias,
                                                  unsigned long long* ring,
                                                  float* __restrict__ out) {
  const int tid = threadIdx.x;
  const int lane = tid & 63;
  const int w = tid >> 6;             // wave 0..3
  const int blk = blockIdx.x;         // 0..63
  const int gi = blk >> 3;            // batch group: batches [8gi, +8)
  const int j = blk & 7;              // unit block:  units   [64j, +64)
  const int u0 = j * 64 + w * 16;     // this wave's 16-unit slice
  const int col = lane & 15;
  const int krow = lane >> 4;         // 0..3
  const int hrow = col & 7;           // LDS h row this lane's A-frag reads

  unsigned long long* ring_g = ring + (size_t)gi * 4096;   // u64[2][8][256]

  __shared__ alignas(16) unsigned short hlds[8][512];      // XOR-swizzled chunks

  // weights: plain loads, compiler-managed (r11/r13-proven)
  short8 Bf[3][16];
#pragma unroll
  for (int g3 = 0; g3 < 3; g3++)
#pragma unroll
    for (int ks = 0; ks < 16; ks++)
      Bf[g3][ks] = *(const short8*)(Rt + (size_t)(g3 * 512 + u0 + col) * 512 + ks * 32 + krow * 8);

  const float br0 = bias[1536 + 0 * 512 + u0 + col];
  const float br1 = bias[1536 + 1 * 512 + u0 + col];
  const float br2 = bias[1536 + 2 * 512 + u0 + col];

  float hreg[4] = {0.f, 0.f, 0.f, 0.f};

  // coop staging chunks: c1 = tid (rows 0..3), c2 = tid+256 (rows 4..7);
  // chunk c covers ring words 4c..4c+3 (= units 8*(c&63)..+8 of batch c>>6)
  const int c1 = tid, c2 = tid + 256;
  const int r1 = c1 >> 6, c1s = (c1 & 63) ^ r1;
  const int r2 = c2 >> 6, c2s = (c2 & 63) ^ r2;

  unsigned short xc[3][4], xn[3][4];
#pragma unroll
  for (int g3 = 0; g3 < 3; g3++)
#pragma unroll
    for (int i = 0; i < 4; i++) {
      int batch = gi * 8 + ((krow * 4 + i) & 7);
      xc[g3][i] = XM[(size_t)batch * 1536 + g3 * 512 + u0 + col];
    }

#pragma unroll 1
  for (int t = 0; t < 1024; ++t) {
    f32x4 acc0 = (f32x4){0.f, 0.f, 0.f, 0.f};
    f32x4 acc1 = acc0, acc2 = acc0;

    if (t > 0) {
      // ---- cooperative tagged slice load: the load IS the poll ----
      const unsigned tagv = (unsigned)t;
      const unsigned long long* rp = ring_g + (size_t)((t + 1) & 1) * 2048;
      unsigned long long q[8];
      for (;;) {
        unsigned bad = 0;
#pragma unroll
        for (int k = 0; k < 4; ++k) {
          q[k] = __hip_atomic_load(rp + 4 * c1 + k, __ATOMIC_RELAXED,
                                   __HIP_MEMORY_SCOPE_AGENT);
          q[4 + k] = __hip_atomic_load(rp + 4 * c2 + k, __ATOMIC_RELAXED,
                                       __HIP_MEMORY_SCOPE_AGENT);
        }
#pragma unroll
        for (int k = 0; k < 8; ++k) bad |= ((unsigned)(q[k] >> 32)) ^ tagv;
        if (__all((int)(bad == 0))) break;
        __builtin_amdgcn_s_sleep(1);
      }

      // ---- swizzled LDS write (2 x 16B per thread, conflict-free) ----
      *(u32x4*)&hlds[r1][c1s * 8] =
          (u32x4){(unsigned)q[0], (unsigned)q[1], (unsigned)q[2], (unsigned)q[3]};
      *(u32x4*)&hlds[r2][c2s * 8] =
          (u32x4){(unsigned)q[4], (unsigned)q[5], (unsigned)q[6], (unsigned)q[7]};
      __syncthreads();

      // ---- fragments from LDS + MFMA ----
      short8 Af[16];
#pragma unroll
      for (int ks = 0; ks < 16; ++ks)
        Af[ks] = *(const short8*)&hlds[hrow][(((ks << 2) + krow) ^ hrow) * 8];
      __syncthreads();   // protect hlds reuse next iteration (no producer barrier now)
#pragma unroll
      for (int ks = 0; ks < 16; ++ks) {
        acc0 = __builtin_amdgcn_mfma_f32_16x16x32_bf16(Af[ks], Bf[0][ks], acc0, 0, 0, 0);
        acc1 = __builtin_amdgcn_mfma_f32_16x16x32_bf16(Af[ks], Bf[1][ks], acc1, 0, 0, 0);
        acc2 = __builtin_amdgcn_mfma_f32_16x16x32_bf16(Af[ks], Bf[2][ks], acc2, 0, 0, 0);
      }
    }

    // gates (fp32); identical arithmetic since r2. krow>=2 rows are benign dups.
#pragma unroll
    for (int i = 0; i < 4; i++) {
      float hz = acc0[i] + br0;
      float hr = acc1[i] + br1;
      float hh = acc2[i] + br2;
      float xz = bf2f(xc[0][i]);
      float xr = bf2f(xc[1][i]);
      float xh = bf2f(xc[2][i]);
      float z = 1.f / (1.f + __expf(-(xz + hz)));
      float r = 1.f / (1.f + __expf(-(xr + hr)));
      float y = xh + r * hh;
      float ay = fabsf(y);
      float e = __expf(-2.f * ay);
      float ca = (1.f - e) / (1.f + e);          // |tanh|
      ca = (y < 0.f) ? -ca : ca;
      hreg[i] = z * hreg[i] + (1.f - z) * ca;
    }

    if (t < 1023) {
      // producer: tagged stores only. Tag travels with data; depth-2 safety by
      // dataflow induction (r8). No drain, no barrier, no flag.
      unsigned long long* hw = ring_g + (size_t)(t & 1) * 2048;
      const unsigned long long tagbits = ((unsigned long long)(unsigned)(t + 1)) << 32;
#pragma unroll
      for (int i = 0; i < 4; i++) {
        int lb = krow * 4 + i;              // local batch; valid when krow<2
        float other = __shfl_xor(hreg[i], 1);
        if (krow < 2 && (col & 1) == 0) {
          unsigned d = (unsigned)f2bf(hreg[i]) | ((unsigned)f2bf(other) << 16);
          __hip_atomic_store(hw + (size_t)lb * 256 + ((u0 + col) >> 1),
                             tagbits | (unsigned long long)d,
                             __ATOMIC_RELAXED, __HIP_MEMORY_SCOPE_AGENT);
        }
      }
    }

    // XM prefetch for t+1 (off the critical store path)
    const int tn = (t < 1023) ? t + 1 : 1023;
#pragma unroll
    for (int g3 = 0; g3 < 3; g3++)
#pragma unroll
      for (int i = 0; i < 4; i++) {
        int batch = gi * 8 + ((krow * 4 + i) & 7);
        xn[g3][i] = XM[(size_t)(tn * 64 + batch) * 1536 + g3 * 512 + u0 + col];
      }
#pragma unroll
    for (int g3 = 0; g3 < 3; g3++)
#pragma unroll
      for (int i = 0; i < 4; i++) xc[g3][i] = xn[g3][i];
  }

  if (krow < 2) {
#pragma unroll
    for (int i = 0; i < 4; i++)
      out[(size_t)(gi * 8 + krow * 4 + i) * 512 + u0 + col] = hreg[i];
  }
}

// ---------------- launch ----------------
extern "C" void kernel_launch(void* const* d_in, const int* in_sizes, int n_in,
                              void* d_out, int out_size, void* d_ws, size_t ws_size,
                              hipStream_t stream) {
  const float* x = (const float*)d_in[0];       // [64][1024][512]
  const float* W = (const float*)d_in[1];       // [512][1536]
  const float* R = (const float*)d_in[2];       // [512][1536]
  const float* bias = (const float*)d_in[3];    // [2][1536]
  float* out = (float*)d_out;

  char* ws = (char*)d_ws;
  unsigned short* Wt = (unsigned short*)(ws + 135168);
  unsigned long long* ring = (unsigned long long*)(ws + 135168);  // overlays Wt
  unsigned short* Rt = (unsigned short*)(ws + 1708032);
  unsigned short* XM = (unsigned short*)(ws + 3280896);

  transpose_cast<<<dim3(48, 16), dim3(32, 8), 0, stream>>>(W, Wt, 512, 1536);
  transpose_cast<<<dim3(48, 16), dim3(32, 8), 0, stream>>>(R, Rt, 512, 1536);
  xm_gemm<<<dim3(512, 12), dim3(256), 0, stream>>>(x, Wt, bias, XM);
  // Wt dead now; zero the tagged ring (tag 0 matches no step t in [1,1024]).
  hipMemsetAsync(ring, 0, 8ull * 2 * 8 * 256 * 8, stream);
  gru_rec<<<dim3(64), dim3(256), 0, stream>>>(Rt, XM, bias, ring, out);
}